// Round 10
// baseline (1058.260 us; speedup 1.0000x reference)
//
#include <hip/hip_runtime.h>
#include <math.h>

#define NN 50000
#define NE 1000000

constexpr float kC121    = 2.1213203435596424f;
constexpr float kSqrt3   = 1.7320508075688772f;
constexpr float kInvSqrt2= 0.7071067811865475f;
constexpr float kInvSqrt8= 0.35355339059327373f;
constexpr float kInvSqrt3= 0.5773502691896258f;
constexpr float kInvSqrt5= 0.4472135954999579f;
constexpr float kSqrt2   = 1.4142135623730951f;
constexpr float kPi      = 3.14159265358979323846f;

__device__ __forceinline__ float swishf(float x){
    return x / (1.0f + __expf(-x));
}

// Distinct repetition macros (preprocessor won't re-expand a macro inside
// its own expansion).
#define REP64A(M) M(0) M(1) M(2) M(3) M(4) M(5) M(6) M(7) M(8) M(9) \
 M(10) M(11) M(12) M(13) M(14) M(15) M(16) M(17) M(18) M(19) \
 M(20) M(21) M(22) M(23) M(24) M(25) M(26) M(27) M(28) M(29) \
 M(30) M(31) M(32) M(33) M(34) M(35) M(36) M(37) M(38) M(39) \
 M(40) M(41) M(42) M(43) M(44) M(45) M(46) M(47) M(48) M(49) \
 M(50) M(51) M(52) M(53) M(54) M(55) M(56) M(57) M(58) M(59) \
 M(60) M(61) M(62) M(63)
#define REP64B(M) M(0) M(1) M(2) M(3) M(4) M(5) M(6) M(7) M(8) M(9) \
 M(10) M(11) M(12) M(13) M(14) M(15) M(16) M(17) M(18) M(19) \
 M(20) M(21) M(22) M(23) M(24) M(25) M(26) M(27) M(28) M(29) \
 M(30) M(31) M(32) M(33) M(34) M(35) M(36) M(37) M(38) M(39) \
 M(40) M(41) M(42) M(43) M(44) M(45) M(46) M(47) M(48) M(49) \
 M(50) M(51) M(52) M(53) M(54) M(55) M(56) M(57) M(58) M(59) \
 M(60) M(61) M(62) M(63)

// ---- MLP core ----------------------------------------------------------
// Inputs in scope: r0..r7, W1T (64x8 transposed), W2 (ORIGINAL 64x64
// row-major, k-outer consumes rows), W3 (64x8). Defines m0..m7.
// k-outer stage 2: each h_k read ONCE (64 accesses vs round-6's 4096) so
// perf no longer depends on whether h lands in arch VGPRs or AGPRs.
#define STAGE1(J) float h_##J; { const float* w = W1T + (J)*8; \
    float a = fmaf(r0,w[0],fmaf(r1,w[1],fmaf(r2,w[2],fmaf(r3,w[3], \
              fmaf(r4,w[4],fmaf(r5,w[5],fmaf(r6,w[6],r7*w[7]))))))); \
    h_##J = swishf(a*kInvSqrt8); }
#define DECLACC(J) float acc_##J = 0.f;
#define UPD(J) acc_##J = fmaf(hk, w2r[J], acc_##J);
#define KSTEP(K) { float hk = h_##K; const float* w2r = W2 + (K)*64; REP64B(UPD) }
#define S3(J) { float a = swishf(acc_##J*0.125f); const float* w3 = W3 + (J)*8; \
    m0=fmaf(a,w3[0],m0); m1=fmaf(a,w3[1],m1); m2=fmaf(a,w3[2],m2); m3=fmaf(a,w3[3],m3); \
    m4=fmaf(a,w3[4],m4); m5=fmaf(a,w3[5],m5); m6=fmaf(a,w3[6],m6); m7=fmaf(a,w3[7],m7); }

#define MLP_BODY \
    float m0=0.f,m1=0.f,m2=0.f,m3=0.f,m4=0.f,m5=0.f,m6=0.f,m7=0.f; \
    { \
    REP64A(STAGE1) \
    REP64A(DECLACC) \
    REP64A(KSTEP) \
    REP64A(S3) \
    } \
    m0*=0.125f; m1*=0.125f; m2*=0.125f; m3*=0.125f; \
    m4*=0.125f; m5*=0.125f; m6*=0.125f; m7*=0.125f;

// ------------------------------------------------------------------------

__global__ void transpose_w1(const float* __restrict__ W1, float* __restrict__ W1T){
    int i = blockIdx.x*blockDim.x + threadIdx.x;
    if (i < 3*8*64){
        int l = i/512, r = i%512; int k = r/64, j = r%64;
        W1T[l*512 + j*8 + k] = W1[i];
    }
}

// ---- CSR build (once per call; receivers are call-constant) ------------
__global__ void hist_rcv(const int* __restrict__ rcv, int* __restrict__ cnt){
    int e = blockIdx.x*blockDim.x + threadIdx.x;
    if (e < NE) atomicAdd(&cnt[rcv[e]], 1);
}

// one block of 1024 threads (16 waves): exclusive scan via wave shuffles.
__global__ void exscan(const int* __restrict__ cnt, int* __restrict__ rowptr,
                       int* __restrict__ wcur){
    __shared__ int wsum[16];
    __shared__ int carry_s;
    int tid = threadIdx.x;
    int lane = tid & 63, wv = tid >> 6;
    if (tid==0) carry_s = 0;
    __syncthreads();
    for (int base=0; base<NN; base+=4096){
        int i0 = base + tid*4;
        int v0 = (i0+0<NN)?cnt[i0+0]:0;
        int v1 = (i0+1<NN)?cnt[i0+1]:0;
        int v2 = (i0+2<NN)?cnt[i0+2]:0;
        int v3 = (i0+3<NN)?cnt[i0+3]:0;
        int t = v0+v1+v2+v3;
        int sc = t;
        #pragma unroll
        for (int off=1; off<64; off<<=1){
            int u = __shfl_up(sc, off, 64);
            if (lane >= off) sc += u;
        }
        if (lane==63) wsum[wv] = sc;
        __syncthreads();
        if (wv==0 && lane<16){
            int ws = wsum[lane];
            #pragma unroll
            for (int off=1; off<16; off<<=1){
                int u = __shfl_up(ws, off, 64);
                if (lane>=off) ws += u;
            }
            wsum[lane] = ws;
        }
        __syncthreads();
        int carry = carry_s;
        int wbase = (wv==0)?0:wsum[wv-1];
        int ex = carry + wbase + (sc - t);
        if (i0+0<NN){ rowptr[i0+0]=ex; wcur[i0+0]=ex; } ex += v0;
        if (i0+1<NN){ rowptr[i0+1]=ex; wcur[i0+1]=ex; } ex += v1;
        if (i0+2<NN){ rowptr[i0+2]=ex; wcur[i0+2]=ex; } ex += v2;
        if (i0+3<NN){ rowptr[i0+3]=ex; wcur[i0+3]=ex; }
        __syncthreads();
        if (tid==0) carry_s = carry + wsum[15];
        __syncthreads();
    }
    if (threadIdx.x==0) rowptr[NN] = carry_s;
}

__global__ void scatter_edges(const int* __restrict__ snd, const int* __restrict__ rcv,
                              int* __restrict__ wcur,
                              int* __restrict__ slot, int* __restrict__ snd_s){
    int e = blockIdx.x*blockDim.x + threadIdx.x;
    if (e >= NE) return;
    int pos = atomicAdd(&wcur[rcv[e]], 1);
    slot[e] = pos;
    snd_s[pos] = snd[e];
}

__global__ void edge_geom(const float* __restrict__ pos,
                          const int* __restrict__ snd,
                          const int* __restrict__ rcv,
                          const int* __restrict__ slot,
                          float* __restrict__ nhat,
                          float* __restrict__ radial){
    int e = blockIdx.x*blockDim.x + threadIdx.x;
    if (e >= NE) return;
    int s = snd[e], r = rcv[e];
    float vx = pos[r*3+0]-pos[s*3+0];
    float vy = pos[r*3+1]-pos[s*3+1];
    float vz = pos[r*3+2]-pos[s*3+2];
    float len = sqrtf(vx*vx+vy*vy+vz*vz);
    float safe = (len==0.f)?1.f:len;
    float inv = 1.f/safe;
    int p = slot ? slot[e] : e;
    nhat[p*3+0]=vx*inv; nhat[p*3+1]=vy*inv; nhat[p*3+2]=vz*inv;
    float x = len;
    float x3=x*x*x, x6=x3*x3, x7=x6*x, x8=x7*x;
    float poly = 1.f - 28.f*x6 + 48.f*x7 - 21.f*x8;
    float env = (x<1.f)?poly:0.f;
    float c = kSqrt2*env*inv;
    float s1, c1;
    __sincosf(kPi*len, &s1, &c1);
    float tc = 2.f*c1;
    float sk_m1 = 0.f, sk = s1;
    float zero = (len==0.f)?0.f:1.f;
    #pragma unroll
    for (int k=1;k<=8;k++){
        radial[p*8+k-1] = sk*c*zero;
        float nxt = tc*sk - sk_m1;
        sk_m1 = sk; sk = nxt;
    }
}

__global__ void node_init(const float* __restrict__ nf,
                          float* __restrict__ s, float* __restrict__ v){
    int n = blockIdx.x*blockDim.x + threadIdx.x;
    if (n >= NN) return;
    s[n] = nf[n*7];
    #pragma unroll
    for (int i=0;i<6;i++) v[n*6+i] = nf[n*7+1+i];
}

__global__ void node_pre(const float* __restrict__ s, const float* __restrict__ v,
                         const float* __restrict__ Wss, const float* __restrict__ Wsv,
                         const float* __restrict__ Wus, const float* __restrict__ Wuv,
                         float* __restrict__ s_sc, float* __restrict__ v_sc,
                         float* __restrict__ su, float* __restrict__ vu){
    int n = blockIdx.x*blockDim.x + threadIdx.x;
    if (n >= NN) return;
    float sv = s[n];
    float vv[6];
    #pragma unroll
    for (int i=0;i<6;i++) vv[i] = v[n*6+i];
    #pragma unroll
    for (int i=0;i<3;i++) s_sc[n*3+i] = sv*Wss[i];
    #pragma unroll
    for (int k=0;k<2;k++)
        #pragma unroll
        for (int c=0;c<3;c++)
            v_sc[n*6+k*3+c] = (vv[c]*Wsv[0*2+k] + vv[3+c]*Wsv[1*2+k]) * kInvSqrt2;
    su[n] = sv * Wus[0];
    #pragma unroll
    for (int k=0;k<2;k++)
        #pragma unroll
        for (int c=0;c<3;c++)
            vu[n*6+k*3+c] = (vv[c]*Wuv[0*2+k] + vv[3+c]*Wuv[1*2+k]) * kInvSqrt2;
}

// ---- sorted path: per-edge message -> plain stores (no atomics) --------
// (256,3): ~168-VGPR cap so h[64]+acc[64] can both live in arch VGPRs.
__global__ void __launch_bounds__(256, 3) edge_msg2(
    const int* __restrict__ snd_s,
    const float* __restrict__ nhat, const float* __restrict__ radial,
    const float* __restrict__ su, const float* __restrict__ vu,
    const float* __restrict__ W1T, const float* __restrict__ W2,
    const float* __restrict__ W3,
    float* __restrict__ msg){
    int sidx = blockIdx.x*blockDim.x + threadIdx.x;
    if (sidx >= NE) return;

    float r0 = radial[sidx*8+0], r1 = radial[sidx*8+1], r2 = radial[sidx*8+2], r3 = radial[sidx*8+3];
    float r4 = radial[sidx*8+4], r5 = radial[sidx*8+5], r6 = radial[sidx*8+6], r7 = radial[sidx*8+7];

    MLP_BODY

    int sn = snd_s[sidx];
    float se = su[sn];
    float ve[6];
    #pragma unroll
    for (int i=0;i<6;i++) ve[i] = vu[sn*6+i];
    float nh[3];
    #pragma unroll
    for (int c=0;c<3;c++) nh[c] = nhat[sidx*3+c];
    float vd0 = ve[0]*nh[0]+ve[1]*nh[1]+ve[2]*nh[2];
    float vd1 = ve[3]*nh[0]+ve[4]*nh[1]+ve[5]*nh[2];

    float* mp = msg + (size_t)sidx*18;
    mp[0] = se *m0;
    mp[1] = vd0*m1;
    mp[2] = vd1*m2;
    #pragma unroll
    for (int c=0;c<3;c++){
        mp[3 +c] = ve[c]*m3;
        mp[6 +c] = ve[3+c]*m4;
        mp[9 +c] = kC121*(vd0*nh[c]-ve[c]*(1.f/3.f))*m5;
        mp[12+c] = kC121*(vd1*nh[c]-ve[3+c]*(1.f/3.f))*m6;
        mp[15+c] = kSqrt3*se*nh[c]*m7;
    }
}

// one thread per (node, col): sum the CSR row
__global__ void agg18(const float* __restrict__ msg, const int* __restrict__ rowptr,
                      float* __restrict__ agg){
    int t = blockIdx.x*blockDim.x + threadIdx.x;
    if (t >= NN*18) return;
    int n = t/18, c = t%18;
    int b = rowptr[n], e = rowptr[n+1];
    float acc = 0.f;
    for (int s=b; s<e; ++s) acc += msg[(size_t)s*18+c];
    agg[t] = acc;
}

__global__ void node_post18(const float* __restrict__ agg,
                            const float* __restrict__ Wds, const float* __restrict__ Wdv,
                            const float* __restrict__ s_sc, const float* __restrict__ v_sc,
                            float* __restrict__ s, float* __restrict__ v,
                            float* __restrict__ out, int is_last){
    int n = blockIdx.x*blockDim.x + threadIdx.x;
    if (n >= NN) return;
    const float* a = agg + n*18;
    float st[3];
    #pragma unroll
    for (int i=0;i<3;i++)
        st[i] = (a[0]*Wds[0*3+i]+a[1]*Wds[1*3+i]+a[2]*Wds[2*3+i])*kInvSqrt3 + s_sc[n*3+i];
    float vt[6];
    #pragma unroll
    for (int k=0;k<2;k++)
        #pragma unroll
        for (int c=0;c<3;c++){
            float acc = 0.f;
            #pragma unroll
            for (int m=0;m<5;m++) acc += a[3+m*3+c]*Wdv[m*2+k];
            vt[k*3+c] = acc*kInvSqrt5 + v_sc[n*6+k*3+c];
        }
    float snew = swishf(st[0]);
    float g1 = swishf(st[1]), g2 = swishf(st[2]);
    s[n] = snew;
    #pragma unroll
    for (int c=0;c<3;c++){
        float v0 = vt[c]*g1;
        float v1 = vt[3+c]*g2;
        v[n*6+c]   = v0;
        v[n*6+3+c] = v1;
        if (is_last) out[n*3+c] = v0;
    }
}

// ---- fallback path (atomics) ------------------------------------------
__global__ void __launch_bounds__(256, 3) edge_msg_atomic(
    const int* __restrict__ snd, const int* __restrict__ rcv,
    const float* __restrict__ nhat, const float* __restrict__ radial,
    const float* __restrict__ su, const float* __restrict__ vu,
    const float* __restrict__ W1T, const float* __restrict__ W2,
    const float* __restrict__ W3,
    float* __restrict__ aggs, float* __restrict__ aggv){
    int e = blockIdx.x*blockDim.x + threadIdx.x;
    if (e >= NE) return;

    float r0 = radial[e*8+0], r1 = radial[e*8+1], r2 = radial[e*8+2], r3 = radial[e*8+3];
    float r4 = radial[e*8+4], r5 = radial[e*8+5], r6 = radial[e*8+6], r7 = radial[e*8+7];

    MLP_BODY

    int sn = snd[e], rn = rcv[e];
    float se = su[sn];
    float ve[6];
    #pragma unroll
    for (int i=0;i<6;i++) ve[i] = vu[sn*6+i];
    float nh[3];
    #pragma unroll
    for (int c=0;c<3;c++) nh[c] = nhat[e*3+c];
    float vd0 = ve[0]*nh[0]+ve[1]*nh[1]+ve[2]*nh[2];
    float vd1 = ve[3]*nh[0]+ve[4]*nh[1]+ve[5]*nh[2];

    atomicAdd(&aggs[rn*3+0], se *m0);
    atomicAdd(&aggs[rn*3+1], vd0*m1);
    atomicAdd(&aggs[rn*3+2], vd1*m2);
    #pragma unroll
    for (int c=0;c<3;c++){
        atomicAdd(&aggv[rn*15+0 +c], ve[c]*m3);
        atomicAdd(&aggv[rn*15+3 +c], ve[3+c]*m4);
        atomicAdd(&aggv[rn*15+6 +c], kC121*(vd0*nh[c]-ve[c]*(1.f/3.f))*m5);
        atomicAdd(&aggv[rn*15+9 +c], kC121*(vd1*nh[c]-ve[3+c]*(1.f/3.f))*m6);
        atomicAdd(&aggv[rn*15+12+c], kSqrt3*se*nh[c]*m7);
    }
}

__global__ void node_post_split(const float* __restrict__ aggs, const float* __restrict__ aggv,
                                const float* __restrict__ Wds, const float* __restrict__ Wdv,
                                const float* __restrict__ s_sc, const float* __restrict__ v_sc,
                                float* __restrict__ s, float* __restrict__ v,
                                float* __restrict__ out, int is_last){
    int n = blockIdx.x*blockDim.x + threadIdx.x;
    if (n >= NN) return;
    float as[3];
    #pragma unroll
    for (int j=0;j<3;j++) as[j] = aggs[n*3+j];
    float st[3];
    #pragma unroll
    for (int i=0;i<3;i++)
        st[i] = (as[0]*Wds[0*3+i]+as[1]*Wds[1*3+i]+as[2]*Wds[2*3+i])*kInvSqrt3 + s_sc[n*3+i];
    float vt[6];
    #pragma unroll
    for (int k=0;k<2;k++)
        #pragma unroll
        for (int c=0;c<3;c++){
            float acc = 0.f;
            #pragma unroll
            for (int m=0;m<5;m++) acc += aggv[n*15+m*3+c]*Wdv[m*2+k];
            vt[k*3+c] = acc*kInvSqrt5 + v_sc[n*6+k*3+c];
        }
    float snew = swishf(st[0]);
    float g1 = swishf(st[1]), g2 = swishf(st[2]);
    s[n] = snew;
    #pragma unroll
    for (int c=0;c<3;c++){
        float v0 = vt[c]*g1;
        float v1 = vt[3+c]*g2;
        v[n*6+c]   = v0;
        v[n*6+3+c] = v1;
        if (is_last) out[n*3+c] = v0;
    }
}

extern "C" void kernel_launch(void* const* d_in, const int* in_sizes, int n_in,
                              void* d_out, int out_size, void* d_ws, size_t ws_size,
                              hipStream_t stream){
    const float* pos = (const float*)d_in[0];
    const float* nf  = (const float*)d_in[1];
    const int*   snd = (const int*)d_in[2];
    const int*   rcv = (const int*)d_in[3];
    const float* Wss = (const float*)d_in[4];
    const float* Wsv = (const float*)d_in[5];
    const float* Wus = (const float*)d_in[6];
    const float* Wuv = (const float*)d_in[7];
    const float* W1  = (const float*)d_in[8];
    const float* W2  = (const float*)d_in[9];
    const float* W3  = (const float*)d_in[10];
    const float* Wds = (const float*)d_in[11];
    const float* Wdv = (const float*)d_in[12];
    float* out = (float*)d_out;

    dim3 blk(256);
    dim3 gE((NE+255)/256), gN((NN+255)/256);

    size_t need_sorted = ((size_t)NE*(3+8+18) + (size_t)NN*(1+6+3+6+1+6+18) + 1536 + 12288)*4
                       + ((size_t)NN*3 + 1 + (size_t)NE*2)*4;

    if (ws_size >= need_sorted){
        float* p = (float*)d_ws;
        float* nhat_s  = p; p += (size_t)NE*3;
        float* radial_s= p; p += (size_t)NE*8;
        float* msg     = p; p += (size_t)NE*18;
        float* s       = p; p += NN;
        float* v       = p; p += NN*6;
        float* s_sc    = p; p += NN*3;
        float* v_sc    = p; p += NN*6;
        float* su      = p; p += NN;
        float* vu      = p; p += NN*6;
        float* agg     = p; p += NN*18;
        float* W1T     = p; p += 1536;
        float* W2T_unused = p; p += 12288;
        (void)W2T_unused;
        int* ip = (int*)p;
        int* cnt    = ip; ip += NN;
        int* rowptr = ip; ip += NN+1;
        int* wcur   = ip; ip += NN;
        int* slot   = ip; ip += NE;
        int* snd_s  = ip; ip += NE;

        transpose_w1<<<dim3((1536+255)/256), blk, 0, stream>>>(W1, W1T);
        hipMemsetAsync(cnt, 0, NN*sizeof(int), stream);
        hist_rcv<<<gE, blk, 0, stream>>>(rcv, cnt);
        exscan<<<dim3(1), dim3(1024), 0, stream>>>(cnt, rowptr, wcur);
        scatter_edges<<<gE, blk, 0, stream>>>(snd, rcv, wcur, slot, snd_s);
        edge_geom<<<gE, blk, 0, stream>>>(pos, snd, rcv, slot, nhat_s, radial_s);
        node_init<<<gN, blk, 0, stream>>>(nf, s, v);
        for (int l=0;l<3;l++){
            node_pre<<<gN, blk, 0, stream>>>(
                s, v, Wss+l*3, Wsv+l*4, Wus+l, Wuv+l*4, s_sc, v_sc, su, vu);
            edge_msg2<<<gE, blk, 0, stream>>>(
                snd_s, nhat_s, radial_s, su, vu,
                W1T+l*512, W2+l*4096, W3+l*512, msg);
            agg18<<<dim3((NN*18+255)/256), blk, 0, stream>>>(msg, rowptr, agg);
            node_post18<<<gN, blk, 0, stream>>>(
                agg, Wds+l*9, Wdv+l*10, s_sc, v_sc, s, v, out, (l==2)?1:0);
        }
    } else {
        float* p = (float*)d_ws;
        float* nhat   = p; p += (size_t)NE*3;
        float* radial = p; p += (size_t)NE*8;
        float* s      = p; p += NN;
        float* v      = p; p += NN*6;
        float* s_sc   = p; p += NN*3;
        float* v_sc   = p; p += NN*6;
        float* su     = p; p += NN;
        float* vu     = p; p += NN*6;
        float* aggs   = p; p += NN*3;
        float* aggv   = p; p += NN*15;
        float* W1T    = p; p += 1536;

        transpose_w1<<<dim3((1536+255)/256), blk, 0, stream>>>(W1, W1T);
        edge_geom<<<gE, blk, 0, stream>>>(pos, snd, rcv, nullptr, nhat, radial);
        node_init<<<gN, blk, 0, stream>>>(nf, s, v);
        for (int l=0;l<3;l++){
            node_pre<<<gN, blk, 0, stream>>>(
                s, v, Wss+l*3, Wsv+l*4, Wus+l, Wuv+l*4, s_sc, v_sc, su, vu);
            hipMemsetAsync(aggs, 0, NN*3*sizeof(float), stream);
            hipMemsetAsync(aggv, 0, NN*15*sizeof(float), stream);
            edge_msg_atomic<<<gE, blk, 0, stream>>>(
                snd, rcv, nhat, radial, su, vu,
                W1T+l*512, W2+l*4096, W3+l*512, aggs, aggv);
            node_post_split<<<gN, blk, 0, stream>>>(
                aggs, aggv, Wds+l*9, Wdv+l*10, s_sc, v_sc, s, v, out, (l==2)?1:0);
        }
    }
}

// Round 12
// 596.415 us; speedup vs baseline: 1.7744x; 1.7744x over previous
//
#include <hip/hip_runtime.h>
#include <math.h>

#define NN 50000
#define NE 1000000

typedef __attribute__((ext_vector_type(8))) short bf16x8;
typedef __attribute__((ext_vector_type(4))) float f32x4;

constexpr float kC121    = 2.1213203435596424f;
constexpr float kSqrt3   = 1.7320508075688772f;
constexpr float kInvSqrt2= 0.7071067811865475f;
constexpr float kInvSqrt8= 0.35355339059327373f;
constexpr float kInvSqrt3= 0.5773502691896258f;
constexpr float kInvSqrt5= 0.4472135954999579f;
constexpr float kSqrt2   = 1.4142135623730951f;
constexpr float kPi      = 3.14159265358979323846f;

__device__ __forceinline__ float swishf(float x){
    return x / (1.0f + __expf(-x));
}
__device__ __forceinline__ unsigned short f2bf(float f){
    unsigned int u = __float_as_uint(f);
    u += 0x7fffu + ((u>>16)&1u);            // RNE f32 -> bf16
    return (unsigned short)(u>>16);
}

// ---- scalar-MLP macros (fallback path only) ----------------------------
#define REP64A(M) M(0) M(1) M(2) M(3) M(4) M(5) M(6) M(7) M(8) M(9) \
 M(10) M(11) M(12) M(13) M(14) M(15) M(16) M(17) M(18) M(19) \
 M(20) M(21) M(22) M(23) M(24) M(25) M(26) M(27) M(28) M(29) \
 M(30) M(31) M(32) M(33) M(34) M(35) M(36) M(37) M(38) M(39) \
 M(40) M(41) M(42) M(43) M(44) M(45) M(46) M(47) M(48) M(49) \
 M(50) M(51) M(52) M(53) M(54) M(55) M(56) M(57) M(58) M(59) \
 M(60) M(61) M(62) M(63)
#define REP64B(M) M(0) M(1) M(2) M(3) M(4) M(5) M(6) M(7) M(8) M(9) \
 M(10) M(11) M(12) M(13) M(14) M(15) M(16) M(17) M(18) M(19) \
 M(20) M(21) M(22) M(23) M(24) M(25) M(26) M(27) M(28) M(29) \
 M(30) M(31) M(32) M(33) M(34) M(35) M(36) M(37) M(38) M(39) \
 M(40) M(41) M(42) M(43) M(44) M(45) M(46) M(47) M(48) M(49) \
 M(50) M(51) M(52) M(53) M(54) M(55) M(56) M(57) M(58) M(59) \
 M(60) M(61) M(62) M(63)
#define STAGE1(J) float h_##J; { const float* w = W1T + (J)*8; \
    float a = fmaf(r0,w[0],fmaf(r1,w[1],fmaf(r2,w[2],fmaf(r3,w[3], \
              fmaf(r4,w[4],fmaf(r5,w[5],fmaf(r6,w[6],r7*w[7]))))))); \
    h_##J = swishf(a*kInvSqrt8); }
#define DECLACC(J) float acc_##J = 0.f;
#define UPD(J) acc_##J = fmaf(hk, w2r[J], acc_##J);
#define KSTEP(K) { float hk = h_##K; const float* w2r = W2 + (K)*64; REP64B(UPD) }
#define S3(J) { float a = swishf(acc_##J*0.125f); const float* w3 = W3 + (J)*8; \
    m0=fmaf(a,w3[0],m0); m1=fmaf(a,w3[1],m1); m2=fmaf(a,w3[2],m2); m3=fmaf(a,w3[3],m3); \
    m4=fmaf(a,w3[4],m4); m5=fmaf(a,w3[5],m5); m6=fmaf(a,w3[6],m6); m7=fmaf(a,w3[7],m7); }
#define MLP_BODY \
    float m0=0.f,m1=0.f,m2=0.f,m3=0.f,m4=0.f,m5=0.f,m6=0.f,m7=0.f; \
    { REP64A(STAGE1) REP64A(DECLACC) REP64A(KSTEP) REP64A(S3) } \
    m0*=0.125f; m1*=0.125f; m2*=0.125f; m3*=0.125f; \
    m4*=0.125f; m5*=0.125f; m6*=0.125f; m7*=0.125f;

// ------------------------------------------------------------------------

__global__ void transpose_w1(const float* __restrict__ W1, float* __restrict__ W1T){
    int i = blockIdx.x*blockDim.x + threadIdx.x;
    if (i < 3*8*64){
        int l = i/512, r = i%512; int k = r/64, j = r%64;
        W1T[l*512 + j*8 + k] = W1[i];
    }
}

// Pack W1/W2/W3 into per-lane MFMA A-fragments (bf16), assumed k-map k=8g+i.
// W1F:[l][jt][lane][8]  A[j][k]=W1[k][j] (k<8 else 0)
// W2F:[l][kt][jt][lane][8]  A[j_out][k]=W2[k][j_out]
// W3F:[l][kt][lane][8]  A[m][k=j]=W3[j][m] (m<8 else 0)
__global__ void build_frags(const float* __restrict__ W1, const float* __restrict__ W2,
                            const float* __restrict__ W3,
                            unsigned short* __restrict__ W1F,
                            unsigned short* __restrict__ W2F,
                            unsigned short* __restrict__ W3F){
    int t = blockIdx.x*blockDim.x + threadIdx.x;
    if (t < 3*4*64*8){
        int i=t&7, lane=(t>>3)&63, jt=(t>>9)&3, l=t>>11;
        int g=lane>>4, c=lane&15;
        int k=8*g+i, j=16*jt+c;
        float v = (k<8) ? W1[l*512 + k*64 + j] : 0.f;
        W1F[t] = f2bf(v);
    }
    if (t < 3*2*4*64*8){
        int i=t&7, lane=(t>>3)&63, jt=(t>>9)&3, kt=(t>>11)&1, l=t>>12;
        int g=lane>>4, c=lane&15;
        int k=32*kt+8*g+i, j=16*jt+c;
        W2F[t] = f2bf(W2[l*4096 + k*64 + j]);
    }
    if (t < 3*2*64*8){
        int i=t&7, lane=(t>>3)&63, kt=(t>>9)&1, l=t>>10;
        int g=lane>>4, c=lane&15;
        int k=32*kt+8*g+i;
        float v = (c<8) ? W3[l*512 + k*8 + c] : 0.f;
        W3F[t] = f2bf(v);
    }
}

// ---- CSR build (once per call) -----------------------------------------
__global__ void hist_rcv(const int* __restrict__ rcv, int* __restrict__ cnt){
    int e = blockIdx.x*blockDim.x + threadIdx.x;
    if (e < NE) atomicAdd(&cnt[rcv[e]], 1);
}

__global__ void exscan(const int* __restrict__ cnt, int* __restrict__ rowptr,
                       int* __restrict__ wcur){
    __shared__ int wsum[16];
    __shared__ int carry_s;
    int tid = threadIdx.x;
    int lane = tid & 63, wv = tid >> 6;
    if (tid==0) carry_s = 0;
    __syncthreads();
    for (int base=0; base<NN; base+=4096){
        int i0 = base + tid*4;
        int v0 = (i0+0<NN)?cnt[i0+0]:0;
        int v1 = (i0+1<NN)?cnt[i0+1]:0;
        int v2 = (i0+2<NN)?cnt[i0+2]:0;
        int v3 = (i0+3<NN)?cnt[i0+3]:0;
        int t = v0+v1+v2+v3;
        int sc = t;
        #pragma unroll
        for (int off=1; off<64; off<<=1){
            int u = __shfl_up(sc, off, 64);
            if (lane >= off) sc += u;
        }
        if (lane==63) wsum[wv] = sc;
        __syncthreads();
        if (wv==0 && lane<16){
            int ws = wsum[lane];
            #pragma unroll
            for (int off=1; off<16; off<<=1){
                int u = __shfl_up(ws, off, 64);
                if (lane>=off) ws += u;
            }
            wsum[lane] = ws;
        }
        __syncthreads();
        int carry = carry_s;
        int wbase = (wv==0)?0:wsum[wv-1];
        int ex = carry + wbase + (sc - t);
        if (i0+0<NN){ rowptr[i0+0]=ex; wcur[i0+0]=ex; } ex += v0;
        if (i0+1<NN){ rowptr[i0+1]=ex; wcur[i0+1]=ex; } ex += v1;
        if (i0+2<NN){ rowptr[i0+2]=ex; wcur[i0+2]=ex; } ex += v2;
        if (i0+3<NN){ rowptr[i0+3]=ex; wcur[i0+3]=ex; }
        __syncthreads();
        if (tid==0) carry_s = carry + wsum[15];
        __syncthreads();
    }
    if (threadIdx.x==0) rowptr[NN] = carry_s;
}

__global__ void scatter_edges(const int* __restrict__ snd, const int* __restrict__ rcv,
                              int* __restrict__ wcur,
                              int* __restrict__ slot, int* __restrict__ snd_s){
    int e = blockIdx.x*blockDim.x + threadIdx.x;
    if (e >= NE) return;
    int pos = atomicAdd(&wcur[rcv[e]], 1);
    slot[e] = pos;
    snd_s[pos] = snd[e];
}

__global__ void edge_geom(const float* __restrict__ pos,
                          const int* __restrict__ snd,
                          const int* __restrict__ rcv,
                          const int* __restrict__ slot,
                          float* __restrict__ nhat,
                          float* __restrict__ radial){
    int e = blockIdx.x*blockDim.x + threadIdx.x;
    if (e >= NE) return;
    int s = snd[e], r = rcv[e];
    float vx = pos[r*3+0]-pos[s*3+0];
    float vy = pos[r*3+1]-pos[s*3+1];
    float vz = pos[r*3+2]-pos[s*3+2];
    float len = sqrtf(vx*vx+vy*vy+vz*vz);
    float safe = (len==0.f)?1.f:len;
    float inv = 1.f/safe;
    int p = slot ? slot[e] : e;
    nhat[p*3+0]=vx*inv; nhat[p*3+1]=vy*inv; nhat[p*3+2]=vz*inv;
    float x = len;
    float x3=x*x*x, x6=x3*x3, x7=x6*x, x8=x7*x;
    float poly = 1.f - 28.f*x6 + 48.f*x7 - 21.f*x8;
    float env = (x<1.f)?poly:0.f;
    float c = kSqrt2*env*inv;
    float s1, c1;
    __sincosf(kPi*len, &s1, &c1);
    float tc = 2.f*c1;
    float sk_m1 = 0.f, sk = s1;
    float zero = (len==0.f)?0.f:1.f;
    #pragma unroll
    for (int k=1;k<=8;k++){
        radial[p*8+k-1] = sk*c*zero;
        float nxt = tc*sk - sk_m1;
        sk_m1 = sk; sk = nxt;
    }
}

__global__ void node_init(const float* __restrict__ nf,
                          float* __restrict__ s, float* __restrict__ v){
    int n = blockIdx.x*blockDim.x + threadIdx.x;
    if (n >= NN) return;
    s[n] = nf[n*7];
    #pragma unroll
    for (int i=0;i<6;i++) v[n*6+i] = nf[n*7+1+i];
}

__global__ void node_pre(const float* __restrict__ s, const float* __restrict__ v,
                         const float* __restrict__ Wss, const float* __restrict__ Wsv,
                         const float* __restrict__ Wus, const float* __restrict__ Wuv,
                         float* __restrict__ s_sc, float* __restrict__ v_sc,
                         float* __restrict__ su, float* __restrict__ vu){
    int n = blockIdx.x*blockDim.x + threadIdx.x;
    if (n >= NN) return;
    float sv = s[n];
    float vv[6];
    #pragma unroll
    for (int i=0;i<6;i++) vv[i] = v[n*6+i];
    #pragma unroll
    for (int i=0;i<3;i++) s_sc[n*3+i] = sv*Wss[i];
    #pragma unroll
    for (int k=0;k<2;k++)
        #pragma unroll
        for (int c=0;c<3;c++)
            v_sc[n*6+k*3+c] = (vv[c]*Wsv[0*2+k] + vv[3+c]*Wsv[1*2+k]) * kInvSqrt2;
    su[n] = sv * Wus[0];
    #pragma unroll
    for (int k=0;k<2;k++)
        #pragma unroll
        for (int c=0;c<3;c++)
            vu[n*6+k*3+c] = (vv[c]*Wuv[0*2+k] + vv[3+c]*Wuv[1*2+k]) * kInvSqrt2;
}

// ---- MFMA edge kernel: 1 wave = 64 edges; D[j][edge] orientation -------
// stage1: D1 = W1^T(as A) x radial(as B); swish -> hbuf[edge][j] (bf16)
// stage2: D2 = W2^T x H1 ; swish -> hbuf ; stage3: mix = W3^T x H2.
// All A/B fragments use the SAME assumed k-map (k=8g+i) -> result exact
// for any true hardware k-slot map (A/B maps identical by symmetry).
__global__ void __launch_bounds__(256) edge_msg_mfma(
    const int* __restrict__ snd_s,
    const float* __restrict__ nhat, const float* __restrict__ radial,
    const float* __restrict__ su, const float* __restrict__ vu,
    const unsigned short* __restrict__ W1F, const unsigned short* __restrict__ W2F,
    const unsigned short* __restrict__ W3F,
    float* __restrict__ msg){
    __shared__ unsigned short hbuf_s[4][16*72];   // 16 edges x 72(pad) bf16, per wave
    __shared__ float mixbuf_s[4][64*8];           // 64 edges x 8 mix, per wave
    int tid = threadIdx.x;
    int w = tid>>6, l = tid&63;
    int g = l>>4, c = l&15;
    long base = ((long)blockIdx.x*4 + w)*64;
    if (base >= NE) return;                        // wave-uniform; no block barriers used
    unsigned short* hbuf = hbuf_s[w];
    float* mixbuf = mixbuf_s[w];

    // weight fragments (L2-resident, 16B coalesced)
    bf16x8 w1f[4], w2f[2][4], w3f[2];
    #pragma unroll
    for (int jt=0;jt<4;jt++)
        w1f[jt] = *(const bf16x8*)(W1F + (jt*64 + l)*8);
    #pragma unroll
    for (int kt=0;kt<2;kt++)
        #pragma unroll
        for (int jt=0;jt<4;jt++)
            w2f[kt][jt] = *(const bf16x8*)(W2F + ((kt*4+jt)*64 + l)*8);
    #pragma unroll
    for (int kt=0;kt<2;kt++)
        w3f[kt] = *(const bf16x8*)(W3F + (kt*64 + l)*8);

    #pragma unroll 1
    for (int nt=0; nt<4; ++nt){
        // B fragment of radial: B[k][edge=c], k=8g+i (real k<8 -> g==0 only)
        bf16x8 brad = {0,0,0,0,0,0,0,0};
        if (g==0){
            const float4* rp = (const float4*)(radial + (base + 16*nt + c)*8);
            float4 ra = rp[0], rb = rp[1];
            brad[0]=(short)f2bf(ra.x); brad[1]=(short)f2bf(ra.y);
            brad[2]=(short)f2bf(ra.z); brad[3]=(short)f2bf(ra.w);
            brad[4]=(short)f2bf(rb.x); brad[5]=(short)f2bf(rb.y);
            brad[6]=(short)f2bf(rb.z); brad[7]=(short)f2bf(rb.w);
        }
        // stage 1 + swish + write h1 (lane holds D[j=16jt+4g+i][edge=c])
        #pragma unroll
        for (int jt=0;jt<4;jt++){
            f32x4 z = {0.f,0.f,0.f,0.f};
            f32x4 d1 = __builtin_amdgcn_mfma_f32_16x16x32_bf16(w1f[jt], brad, z, 0,0,0);
            unsigned short b0=f2bf(swishf(d1[0]*kInvSqrt8));
            unsigned short b1=f2bf(swishf(d1[1]*kInvSqrt8));
            unsigned short b2=f2bf(swishf(d1[2]*kInvSqrt8));
            unsigned short b3=f2bf(swishf(d1[3]*kInvSqrt8));
            uint2 pk; pk.x = ((unsigned)b1<<16)|b0; pk.y = ((unsigned)b3<<16)|b2;
            *(uint2*)(hbuf + c*72 + 16*jt + 4*g) = pk;
        }
        // stage 2: read H1 B-fragments (k=32kt+8g+i contiguous at fixed edge row)
        bf16x8 bh0 = *(const bf16x8*)(hbuf + c*72 + 8*g);
        bf16x8 bh1 = *(const bf16x8*)(hbuf + c*72 + 32 + 8*g);
        #pragma unroll
        for (int jt=0;jt<4;jt++){
            f32x4 z = {0.f,0.f,0.f,0.f};
            f32x4 d2 = __builtin_amdgcn_mfma_f32_16x16x32_bf16(w2f[0][jt], bh0, z, 0,0,0);
            d2 = __builtin_amdgcn_mfma_f32_16x16x32_bf16(w2f[1][jt], bh1, d2, 0,0,0);
            unsigned short b0=f2bf(swishf(d2[0]*0.125f));
            unsigned short b1=f2bf(swishf(d2[1]*0.125f));
            unsigned short b2=f2bf(swishf(d2[2]*0.125f));
            unsigned short b3=f2bf(swishf(d2[3]*0.125f));
            uint2 pk; pk.x = ((unsigned)b1<<16)|b0; pk.y = ((unsigned)b3<<16)|b2;
            *(uint2*)(hbuf + c*72 + 16*jt + 4*g) = pk;
        }
        // stage 3
        bf16x8 ch0 = *(const bf16x8*)(hbuf + c*72 + 8*g);
        bf16x8 ch1 = *(const bf16x8*)(hbuf + c*72 + 32 + 8*g);
        f32x4 z3 = {0.f,0.f,0.f,0.f};
        f32x4 mx = __builtin_amdgcn_mfma_f32_16x16x32_bf16(w3f[0], ch0, z3, 0,0,0);
        mx = __builtin_amdgcn_mfma_f32_16x16x32_bf16(w3f[1], ch1, mx, 0,0,0);
        if (g < 2){                                 // rows m=4g+i cover m 0..7
            f32x4 mo = mx * 0.125f;
            *(f32x4*)(mixbuf + (16*nt + c)*8 + 4*g) = mo;
        }
    }

    // epilogue: lane l owns edge base+l
    long e = base + l;
    const float* mr = mixbuf + l*8;
    float mm0=mr[0], mm1=mr[1], mm2=mr[2], mm3=mr[3];
    float mm4=mr[4], mm5=mr[5], mm6=mr[6], mm7=mr[7];
    int sn = snd_s[e];
    float se = su[sn];
    float ve[6];
    #pragma unroll
    for (int i=0;i<6;i++) ve[i] = vu[sn*6+i];
    float nh[3];
    #pragma unroll
    for (int i=0;i<3;i++) nh[i] = nhat[e*3+i];
    float vd0 = ve[0]*nh[0]+ve[1]*nh[1]+ve[2]*nh[2];
    float vd1 = ve[3]*nh[0]+ve[4]*nh[1]+ve[5]*nh[2];
    float* mp = msg + e*18;
    mp[0] = se *mm0;
    mp[1] = vd0*mm1;
    mp[2] = vd1*mm2;
    #pragma unroll
    for (int i=0;i<3;i++){
        mp[3 +i] = ve[i]*mm3;
        mp[6 +i] = ve[3+i]*mm4;
        mp[9 +i] = kC121*(vd0*nh[i]-ve[i]*(1.f/3.f))*mm5;
        mp[12+i] = kC121*(vd1*nh[i]-ve[3+i]*(1.f/3.f))*mm6;
        mp[15+i] = kSqrt3*se*nh[i]*mm7;
    }
}

// one thread per (node, col): sum the CSR row
__global__ void agg18(const float* __restrict__ msg, const int* __restrict__ rowptr,
                      float* __restrict__ agg){
    int t = blockIdx.x*blockDim.x + threadIdx.x;
    if (t >= NN*18) return;
    int n = t/18, c = t%18;
    int b = rowptr[n], e = rowptr[n+1];
    float acc = 0.f;
    for (int s=b; s<e; ++s) acc += msg[(size_t)s*18+c];
    agg[t] = acc;
}

__global__ void node_post18(const float* __restrict__ agg,
                            const float* __restrict__ Wds, const float* __restrict__ Wdv,
                            const float* __restrict__ s_sc, const float* __restrict__ v_sc,
                            float* __restrict__ s, float* __restrict__ v,
                            float* __restrict__ out, int is_last){
    int n = blockIdx.x*blockDim.x + threadIdx.x;
    if (n >= NN) return;
    const float* a = agg + n*18;
    float st[3];
    #pragma unroll
    for (int i=0;i<3;i++)
        st[i] = (a[0]*Wds[0*3+i]+a[1]*Wds[1*3+i]+a[2]*Wds[2*3+i])*kInvSqrt3 + s_sc[n*3+i];
    float vt[6];
    #pragma unroll
    for (int k=0;k<2;k++)
        #pragma unroll
        for (int c=0;c<3;c++){
            float acc = 0.f;
            #pragma unroll
            for (int m=0;m<5;m++) acc += a[3+m*3+c]*Wdv[m*2+k];
            vt[k*3+c] = acc*kInvSqrt5 + v_sc[n*6+k*3+c];
        }
    float snew = swishf(st[0]);
    float g1 = swishf(st[1]), g2 = swishf(st[2]);
    s[n] = snew;
    #pragma unroll
    for (int c=0;c<3;c++){
        float v0 = vt[c]*g1;
        float v1 = vt[3+c]*g2;
        v[n*6+c]   = v0;
        v[n*6+3+c] = v1;
        if (is_last) out[n*3+c] = v0;
    }
}

// ---- fallback path (atomics + scalar MLP), proven correct --------------
__global__ void __launch_bounds__(256, 3) edge_msg_atomic(
    const int* __restrict__ snd, const int* __restrict__ rcv,
    const float* __restrict__ nhat, const float* __restrict__ radial,
    const float* __restrict__ su, const float* __restrict__ vu,
    const float* __restrict__ W1T, const float* __restrict__ W2,
    const float* __restrict__ W3,
    float* __restrict__ aggs, float* __restrict__ aggv){
    int e = blockIdx.x*blockDim.x + threadIdx.x;
    if (e >= NE) return;

    float r0 = radial[e*8+0], r1 = radial[e*8+1], r2 = radial[e*8+2], r3 = radial[e*8+3];
    float r4 = radial[e*8+4], r5 = radial[e*8+5], r6 = radial[e*8+6], r7 = radial[e*8+7];

    MLP_BODY

    int sn = snd[e], rn = rcv[e];
    float se = su[sn];
    float ve[6];
    #pragma unroll
    for (int i=0;i<6;i++) ve[i] = vu[sn*6+i];
    float nh[3];
    #pragma unroll
    for (int c=0;c<3;c++) nh[c] = nhat[e*3+c];
    float vd0 = ve[0]*nh[0]+ve[1]*nh[1]+ve[2]*nh[2];
    float vd1 = ve[3]*nh[0]+ve[4]*nh[1]+ve[5]*nh[2];

    atomicAdd(&aggs[rn*3+0], se *m0);
    atomicAdd(&aggs[rn*3+1], vd0*m1);
    atomicAdd(&aggs[rn*3+2], vd1*m2);
    #pragma unroll
    for (int c=0;c<3;c++){
        atomicAdd(&aggv[rn*15+0 +c], ve[c]*m3);
        atomicAdd(&aggv[rn*15+3 +c], ve[3+c]*m4);
        atomicAdd(&aggv[rn*15+6 +c], kC121*(vd0*nh[c]-ve[c]*(1.f/3.f))*m5);
        atomicAdd(&aggv[rn*15+9 +c], kC121*(vd1*nh[c]-ve[3+c]*(1.f/3.f))*m6);
        atomicAdd(&aggv[rn*15+12+c], kSqrt3*se*nh[c]*m7);
    }
}

__global__ void node_post_split(const float* __restrict__ aggs, const float* __restrict__ aggv,
                                const float* __restrict__ Wds, const float* __restrict__ Wdv,
                                const float* __restrict__ s_sc, const float* __restrict__ v_sc,
                                float* __restrict__ s, float* __restrict__ v,
                                float* __restrict__ out, int is_last){
    int n = blockIdx.x*blockDim.x + threadIdx.x;
    if (n >= NN) return;
    float as[3];
    #pragma unroll
    for (int j=0;j<3;j++) as[j] = aggs[n*3+j];
    float st[3];
    #pragma unroll
    for (int i=0;i<3;i++)
        st[i] = (as[0]*Wds[0*3+i]+as[1]*Wds[1*3+i]+as[2]*Wds[2*3+i])*kInvSqrt3 + s_sc[n*3+i];
    float vt[6];
    #pragma unroll
    for (int k=0;k<2;k++)
        #pragma unroll
        for (int c=0;c<3;c++){
            float acc = 0.f;
            #pragma unroll
            for (int m=0;m<5;m++) acc += aggv[n*15+m*3+c]*Wdv[m*2+k];
            vt[k*3+c] = acc*kInvSqrt5 + v_sc[n*6+k*3+c];
        }
    float snew = swishf(st[0]);
    float g1 = swishf(st[1]), g2 = swishf(st[2]);
    s[n] = snew;
    #pragma unroll
    for (int c=0;c<3;c++){
        float v0 = vt[c]*g1;
        float v1 = vt[3+c]*g2;
        v[n*6+c]   = v0;
        v[n*6+3+c] = v1;
        if (is_last) out[n*3+c] = v0;
    }
}

extern "C" void kernel_launch(void* const* d_in, const int* in_sizes, int n_in,
                              void* d_out, int out_size, void* d_ws, size_t ws_size,
                              hipStream_t stream){
    const float* pos = (const float*)d_in[0];
    const float* nf  = (const float*)d_in[1];
    const int*   snd = (const int*)d_in[2];
    const int*   rcv = (const int*)d_in[3];
    const float* Wss = (const float*)d_in[4];
    const float* Wsv = (const float*)d_in[5];
    const float* Wus = (const float*)d_in[6];
    const float* Wuv = (const float*)d_in[7];
    const float* W1  = (const float*)d_in[8];
    const float* W2  = (const float*)d_in[9];
    const float* W3  = (const float*)d_in[10];
    const float* Wds = (const float*)d_in[11];
    const float* Wdv = (const float*)d_in[12];
    float* out = (float*)d_out;

    dim3 blk(256);
    dim3 gE((NE+255)/256), gN((NN+255)/256);

    // sorted-path workspace: floats + bf16 frag buffers + ints
    size_t need_sorted = ((size_t)NE*29 + (size_t)NN*41)*4
                       + 21504*2
                       + ((size_t)NN*3 + 1 + (size_t)NE*2)*4 + 64;

    if (ws_size >= need_sorted){
        float* p = (float*)d_ws;
        float* nhat_s  = p; p += (size_t)NE*3;
        float* radial_s= p; p += (size_t)NE*8;
        float* msg     = p; p += (size_t)NE*18;
        float* s       = p; p += NN;
        float* v       = p; p += NN*6;
        float* s_sc    = p; p += NN*3;
        float* v_sc    = p; p += NN*6;
        float* su      = p; p += NN;
        float* vu      = p; p += NN*6;
        float* agg     = p; p += NN*18;
        unsigned short* wp = (unsigned short*)p;
        unsigned short* W1F = wp;          wp += 3*4*64*8;    // 6144
        unsigned short* W2F = wp;          wp += 3*2*4*64*8;  // 12288
        unsigned short* W3F = wp;          wp += 3*2*64*8;    // 3072
        int* ip = (int*)wp;
        int* cnt    = ip; ip += NN;
        int* rowptr = ip; ip += NN+1;
        int* wcur   = ip; ip += NN;
        int* slot   = ip; ip += NE;
        int* snd_s  = ip; ip += NE;

        build_frags<<<dim3(48), blk, 0, stream>>>(W1, W2, W3, W1F, W2F, W3F);
        hipMemsetAsync(cnt, 0, NN*sizeof(int), stream);
        hist_rcv<<<gE, blk, 0, stream>>>(rcv, cnt);
        exscan<<<dim3(1), dim3(1024), 0, stream>>>(cnt, rowptr, wcur);
        scatter_edges<<<gE, blk, 0, stream>>>(snd, rcv, wcur, slot, snd_s);
        edge_geom<<<gE, blk, 0, stream>>>(pos, snd, rcv, slot, nhat_s, radial_s);
        node_init<<<gN, blk, 0, stream>>>(nf, s, v);
        dim3 gW((NE/64 + 3)/4);   // 15625 waves, 4 waves/block -> 3907 blocks
        for (int l=0;l<3;l++){
            node_pre<<<gN, blk, 0, stream>>>(
                s, v, Wss+l*3, Wsv+l*4, Wus+l, Wuv+l*4, s_sc, v_sc, su, vu);
            edge_msg_mfma<<<gW, blk, 0, stream>>>(
                snd_s, nhat_s, radial_s, su, vu,
                W1F + l*2048, W2F + l*4096, W3F + l*1024, msg);
            agg18<<<dim3((NN*18+255)/256), blk, 0, stream>>>(msg, rowptr, agg);
            node_post18<<<gN, blk, 0, stream>>>(
                agg, Wds+l*9, Wdv+l*10, s_sc, v_sc, s, v, out, (l==2)?1:0);
        }
    } else {
        float* p = (float*)d_ws;
        float* nhat   = p; p += (size_t)NE*3;
        float* radial = p; p += (size_t)NE*8;
        float* s      = p; p += NN;
        float* v      = p; p += NN*6;
        float* s_sc   = p; p += NN*3;
        float* v_sc   = p; p += NN*6;
        float* su     = p; p += NN;
        float* vu     = p; p += NN*6;
        float* aggs   = p; p += NN*3;
        float* aggv   = p; p += NN*15;
        float* W1T    = p; p += 1536;

        transpose_w1<<<dim3((1536+255)/256), blk, 0, stream>>>(W1, W1T);
        edge_geom<<<gE, blk, 0, stream>>>(pos, snd, rcv, nullptr, nhat, radial);
        node_init<<<gN, blk, 0, stream>>>(nf, s, v);
        for (int l=0;l<3;l++){
            node_pre<<<gN, blk, 0, stream>>>(
                s, v, Wss+l*3, Wsv+l*4, Wus+l, Wuv+l*4, s_sc, v_sc, su, vu);
            hipMemsetAsync(aggs, 0, NN*3*sizeof(float), stream);
            hipMemsetAsync(aggv, 0, NN*15*sizeof(float), stream);
            edge_msg_atomic<<<gE, blk, 0, stream>>>(
                snd, rcv, nhat, radial, su, vu,
                W1T+l*512, W2+l*4096, W3+l*512, aggs, aggv);
            node_post_split<<<gN, blk, 0, stream>>>(
                aggs, aggv, Wds+l*9, Wdv+l*10, s_sc, v_sc, s, v, out, (l==2)?1:0);
        }
    }
}

// Round 13
// 479.525 us; speedup vs baseline: 2.2069x; 1.2438x over previous
//
#include <hip/hip_runtime.h>
#include <hip/hip_bf16.h>
#include <math.h>

#define NN 50000
#define NE 1000000

typedef __attribute__((ext_vector_type(8))) short bf16x8;
typedef __attribute__((ext_vector_type(4))) float f32x4;

constexpr float kC121    = 2.1213203435596424f;
constexpr float kSqrt3   = 1.7320508075688772f;
constexpr float kInvSqrt2= 0.7071067811865475f;
constexpr float kInvSqrt8= 0.35355339059327373f;
constexpr float kInvSqrt3= 0.5773502691896258f;
constexpr float kInvSqrt5= 0.4472135954999579f;
constexpr float kSqrt2   = 1.4142135623730951f;
constexpr float kPi      = 3.14159265358979323846f;

// swish with 1-instr v_rcp (rel err ~1e-7, negligible vs bf16 path)
__device__ __forceinline__ float swishf(float x){
    return x * __builtin_amdgcn_rcpf(1.0f + __expf(-x));
}
__device__ __forceinline__ unsigned short f2bf(float f){
    unsigned int u = __float_as_uint(f);
    u += 0x7fffu + ((u>>16)&1u);
    return (unsigned short)(u>>16);
}
// packed pair f32->bf16 (compiler emits v_cvt_pk_bf16_f32)
__device__ __forceinline__ unsigned int pk2(float a, float b){
    union { __hip_bfloat162 h; unsigned int u; } cv;
    cv.h = __float22bfloat162_rn(make_float2(a,b));
    return cv.u;
}

// ---- scalar-MLP macros (fallback path only) ----------------------------
#define REP64A(M) M(0) M(1) M(2) M(3) M(4) M(5) M(6) M(7) M(8) M(9) \
 M(10) M(11) M(12) M(13) M(14) M(15) M(16) M(17) M(18) M(19) \
 M(20) M(21) M(22) M(23) M(24) M(25) M(26) M(27) M(28) M(29) \
 M(30) M(31) M(32) M(33) M(34) M(35) M(36) M(37) M(38) M(39) \
 M(40) M(41) M(42) M(43) M(44) M(45) M(46) M(47) M(48) M(49) \
 M(50) M(51) M(52) M(53) M(54) M(55) M(56) M(57) M(58) M(59) \
 M(60) M(61) M(62) M(63)
#define REP64B(M) M(0) M(1) M(2) M(3) M(4) M(5) M(6) M(7) M(8) M(9) \
 M(10) M(11) M(12) M(13) M(14) M(15) M(16) M(17) M(18) M(19) \
 M(20) M(21) M(22) M(23) M(24) M(25) M(26) M(27) M(28) M(29) \
 M(30) M(31) M(32) M(33) M(34) M(35) M(36) M(37) M(38) M(39) \
 M(40) M(41) M(42) M(43) M(44) M(45) M(46) M(47) M(48) M(49) \
 M(50) M(51) M(52) M(53) M(54) M(55) M(56) M(57) M(58) M(59) \
 M(60) M(61) M(62) M(63)
#define STAGE1(J) float h_##J; { const float* w = W1T + (J)*8; \
    float a = fmaf(r0,w[0],fmaf(r1,w[1],fmaf(r2,w[2],fmaf(r3,w[3], \
              fmaf(r4,w[4],fmaf(r5,w[5],fmaf(r6,w[6],r7*w[7]))))))); \
    h_##J = swishf(a*kInvSqrt8); }
#define DECLACC(J) float acc_##J = 0.f;
#define UPD(J) acc_##J = fmaf(hk, w2r[J], acc_##J);
#define KSTEP(K) { float hk = h_##K; const float* w2r = W2 + (K)*64; REP64B(UPD) }
#define S3(J) { float a = swishf(acc_##J*0.125f); const float* w3 = W3 + (J)*8; \
    m0=fmaf(a,w3[0],m0); m1=fmaf(a,w3[1],m1); m2=fmaf(a,w3[2],m2); m3=fmaf(a,w3[3],m3); \
    m4=fmaf(a,w3[4],m4); m5=fmaf(a,w3[5],m5); m6=fmaf(a,w3[6],m6); m7=fmaf(a,w3[7],m7); }
#define MLP_BODY \
    float m0=0.f,m1=0.f,m2=0.f,m3=0.f,m4=0.f,m5=0.f,m6=0.f,m7=0.f; \
    { REP64A(STAGE1) REP64A(DECLACC) REP64A(KSTEP) REP64A(S3) } \
    m0*=0.125f; m1*=0.125f; m2*=0.125f; m3*=0.125f; \
    m4*=0.125f; m5*=0.125f; m6*=0.125f; m7*=0.125f;

// ------------------------------------------------------------------------

__global__ void transpose_w1(const float* __restrict__ W1, float* __restrict__ W1T){
    int i = blockIdx.x*blockDim.x + threadIdx.x;
    if (i < 3*8*64){
        int l = i/512, r = i%512; int k = r/64, j = r%64;
        W1T[l*512 + j*8 + k] = W1[i];
    }
}

// Pack W1/W2/W3 into per-lane MFMA A-fragments (bf16), assumed k-map k=8g+i.
// Stage scales FOLDED into the weights: W1*=1/sqrt8, W2*=0.125, W3*=0.125.
__global__ void build_frags(const float* __restrict__ W1, const float* __restrict__ W2,
                            const float* __restrict__ W3,
                            unsigned short* __restrict__ W1F,
                            unsigned short* __restrict__ W2F,
                            unsigned short* __restrict__ W3F){
    int t = blockIdx.x*blockDim.x + threadIdx.x;
    if (t < 3*4*64*8){
        int i=t&7, lane=(t>>3)&63, jt=(t>>9)&3, l=t>>11;
        int g=lane>>4, c=lane&15;
        int k=8*g+i, j=16*jt+c;
        float v = (k<8) ? W1[l*512 + k*64 + j]*kInvSqrt8 : 0.f;
        W1F[t] = f2bf(v);
    }
    if (t < 3*2*4*64*8){
        int i=t&7, lane=(t>>3)&63, jt=(t>>9)&3, kt=(t>>11)&1, l=t>>12;
        int g=lane>>4, c=lane&15;
        int k=32*kt+8*g+i, j=16*jt+c;
        W2F[t] = f2bf(W2[l*4096 + k*64 + j]*0.125f);
    }
    if (t < 3*2*64*8){
        int i=t&7, lane=(t>>3)&63, kt=(t>>9)&1, l=t>>10;
        int g=lane>>4, c=lane&15;
        int k=32*kt+8*g+i;
        float v = (c<8) ? W3[l*512 + k*8 + c]*0.125f : 0.f;
        W3F[t] = f2bf(v);
    }
}

// ---- CSR build (once per call) -----------------------------------------
__global__ void hist_rcv(const int* __restrict__ rcv, int* __restrict__ cnt){
    int e = blockIdx.x*blockDim.x + threadIdx.x;
    if (e < NE) atomicAdd(&cnt[rcv[e]], 1);
}

__global__ void exscan(const int* __restrict__ cnt, int* __restrict__ rowptr,
                       int* __restrict__ wcur){
    __shared__ int wsum[16];
    __shared__ int carry_s;
    int tid = threadIdx.x;
    int lane = tid & 63, wv = tid >> 6;
    if (tid==0) carry_s = 0;
    __syncthreads();
    for (int base=0; base<NN; base+=4096){
        int i0 = base + tid*4;
        int v0 = (i0+0<NN)?cnt[i0+0]:0;
        int v1 = (i0+1<NN)?cnt[i0+1]:0;
        int v2 = (i0+2<NN)?cnt[i0+2]:0;
        int v3 = (i0+3<NN)?cnt[i0+3]:0;
        int t = v0+v1+v2+v3;
        int sc = t;
        #pragma unroll
        for (int off=1; off<64; off<<=1){
            int u = __shfl_up(sc, off, 64);
            if (lane >= off) sc += u;
        }
        if (lane==63) wsum[wv] = sc;
        __syncthreads();
        if (wv==0 && lane<16){
            int ws = wsum[lane];
            #pragma unroll
            for (int off=1; off<16; off<<=1){
                int u = __shfl_up(ws, off, 64);
                if (lane>=off) ws += u;
            }
            wsum[lane] = ws;
        }
        __syncthreads();
        int carry = carry_s;
        int wbase = (wv==0)?0:wsum[wv-1];
        int ex = carry + wbase + (sc - t);
        if (i0+0<NN){ rowptr[i0+0]=ex; wcur[i0+0]=ex; } ex += v0;
        if (i0+1<NN){ rowptr[i0+1]=ex; wcur[i0+1]=ex; } ex += v1;
        if (i0+2<NN){ rowptr[i0+2]=ex; wcur[i0+2]=ex; } ex += v2;
        if (i0+3<NN){ rowptr[i0+3]=ex; wcur[i0+3]=ex; }
        __syncthreads();
        if (tid==0) carry_s = carry + wsum[15];
        __syncthreads();
    }
    if (threadIdx.x==0) rowptr[NN] = carry_s;
}

__global__ void scatter_edges(const int* __restrict__ snd, const int* __restrict__ rcv,
                              int* __restrict__ wcur,
                              int* __restrict__ slot, int* __restrict__ snd_s){
    int e = blockIdx.x*blockDim.x + threadIdx.x;
    if (e >= NE) return;
    int pos = atomicAdd(&wcur[rcv[e]], 1);
    slot[e] = pos;
    snd_s[pos] = snd[e];
}

// geometry; sorted path writes bf16 radial (radial_bf), fallback f32
__global__ void edge_geom(const float* __restrict__ pos,
                          const int* __restrict__ snd,
                          const int* __restrict__ rcv,
                          const int* __restrict__ slot,
                          float* __restrict__ nhat,
                          float* __restrict__ radial_f,
                          unsigned short* __restrict__ radial_bf){
    int e = blockIdx.x*blockDim.x + threadIdx.x;
    if (e >= NE) return;
    int s = snd[e], r = rcv[e];
    float vx = pos[r*3+0]-pos[s*3+0];
    float vy = pos[r*3+1]-pos[s*3+1];
    float vz = pos[r*3+2]-pos[s*3+2];
    float len = sqrtf(vx*vx+vy*vy+vz*vz);
    float safe = (len==0.f)?1.f:len;
    float inv = 1.f/safe;
    int p = slot ? slot[e] : e;
    nhat[p*3+0]=vx*inv; nhat[p*3+1]=vy*inv; nhat[p*3+2]=vz*inv;
    float x = len;
    float x3=x*x*x, x6=x3*x3, x7=x6*x, x8=x7*x;
    float poly = 1.f - 28.f*x6 + 48.f*x7 - 21.f*x8;
    float env = (x<1.f)?poly:0.f;
    float c = kSqrt2*env*inv;
    float s1, c1;
    __sincosf(kPi*len, &s1, &c1);
    float tc = 2.f*c1;
    float sk_m1 = 0.f, sk = s1;
    float zero = (len==0.f)?0.f:1.f;
    float rv[8];
    #pragma unroll
    for (int k=1;k<=8;k++){
        rv[k-1] = sk*c*zero;
        float nxt = tc*sk - sk_m1;
        sk_m1 = sk; sk = nxt;
    }
    if (radial_bf){
        uint4 pk;
        pk.x = pk2(rv[0],rv[1]); pk.y = pk2(rv[2],rv[3]);
        pk.z = pk2(rv[4],rv[5]); pk.w = pk2(rv[6],rv[7]);
        *(uint4*)(radial_bf + (size_t)p*8) = pk;
    } else {
        #pragma unroll
        for (int k=0;k<8;k++) radial_f[p*8+k] = rv[k];
    }
}

// prologue: node_init + node_pre(l=0) fused (s/v arrays not materialized)
__global__ void node_init_pre(const float* __restrict__ nf,
                              const float* __restrict__ Wss, const float* __restrict__ Wsv,
                              const float* __restrict__ Wus, const float* __restrict__ Wuv,
                              float* __restrict__ s_sc, float* __restrict__ v_sc,
                              float* __restrict__ su, float* __restrict__ vu){
    int n = blockIdx.x*blockDim.x + threadIdx.x;
    if (n >= NN) return;
    float sv = nf[n*7];
    float vv[6];
    #pragma unroll
    for (int i=0;i<6;i++) vv[i] = nf[n*7+1+i];
    #pragma unroll
    for (int i=0;i<3;i++) s_sc[n*3+i] = sv*Wss[i];
    #pragma unroll
    for (int k=0;k<2;k++)
        #pragma unroll
        for (int c=0;c<3;c++)
            v_sc[n*6+k*3+c] = (vv[c]*Wsv[0*2+k] + vv[3+c]*Wsv[1*2+k]) * kInvSqrt2;
    su[n] = sv * Wus[0];
    #pragma unroll
    for (int k=0;k<2;k++)
        #pragma unroll
        for (int c=0;c<3;c++)
            vu[n*6+k*3+c] = (vv[c]*Wuv[0*2+k] + vv[3+c]*Wuv[1*2+k]) * kInvSqrt2;
}

// ---- MFMA edge kernel (scales folded; rcp-swish; cvt_pk; XOR swizzle) --
__global__ void __launch_bounds__(256) edge_msg_mfma(
    const int* __restrict__ snd_s,
    const float* __restrict__ nhat, const unsigned short* __restrict__ radial_bf,
    const float* __restrict__ su, const float* __restrict__ vu,
    const unsigned short* __restrict__ W1F, const unsigned short* __restrict__ W2F,
    const unsigned short* __restrict__ W3F,
    float* __restrict__ msg){
    __shared__ unsigned short hbuf_s[4][16*72];   // 16 rows x 144B (128B data+16B pad)
    __shared__ float mixbuf_s[4][64*12];          // 12-float rows: 2-way banks only
    int tid = threadIdx.x;
    int w = tid>>6, l = tid&63;
    int g = l>>4, c = l&15;
    long base = ((long)blockIdx.x*4 + w)*64;
    if (base >= NE) return;
    char* hrow = (char*)hbuf_s[w] + c*144;
    float* mixbuf = mixbuf_s[w];
    int swz = (c&7)<<4;                            // byte XOR, bits 4-6 (bijective in 128B)

    bf16x8 w1f[4], w2f[2][4], w3f[2];
    #pragma unroll
    for (int jt=0;jt<4;jt++)
        w1f[jt] = *(const bf16x8*)(W1F + (jt*64 + l)*8);
    #pragma unroll
    for (int kt=0;kt<2;kt++)
        #pragma unroll
        for (int jt=0;jt<4;jt++)
            w2f[kt][jt] = *(const bf16x8*)(W2F + ((kt*4+jt)*64 + l)*8);
    #pragma unroll
    for (int kt=0;kt<2;kt++)
        w3f[kt] = *(const bf16x8*)(W3F + (kt*64 + l)*8);

    #pragma unroll 1
    for (int nt=0; nt<4; ++nt){
        bf16x8 brad = {0,0,0,0,0,0,0,0};
        if (g==0)
            brad = *(const bf16x8*)(radial_bf + (size_t)(base + 16*nt + c)*8);
        // stage 1 (scale pre-folded)
        #pragma unroll
        for (int jt=0;jt<4;jt++){
            f32x4 z = {0.f,0.f,0.f,0.f};
            f32x4 d1 = __builtin_amdgcn_mfma_f32_16x16x32_bf16(w1f[jt], brad, z, 0,0,0);
            uint2 pk;
            pk.x = pk2(swishf(d1[0]), swishf(d1[1]));
            pk.y = pk2(swishf(d1[2]), swishf(d1[3]));
            *(uint2*)(hrow + ((32*jt + 8*g) ^ swz)) = pk;
        }
        bf16x8 bh0 = *(const bf16x8*)(hrow + ((16*g) ^ swz));
        bf16x8 bh1 = *(const bf16x8*)(hrow + ((64 + 16*g) ^ swz));
        // stage 2
        #pragma unroll
        for (int jt=0;jt<4;jt++){
            f32x4 z = {0.f,0.f,0.f,0.f};
            f32x4 d2 = __builtin_amdgcn_mfma_f32_16x16x32_bf16(w2f[0][jt], bh0, z, 0,0,0);
            d2 = __builtin_amdgcn_mfma_f32_16x16x32_bf16(w2f[1][jt], bh1, d2, 0,0,0);
            uint2 pk;
            pk.x = pk2(swishf(d2[0]), swishf(d2[1]));
            pk.y = pk2(swishf(d2[2]), swishf(d2[3]));
            *(uint2*)(hrow + ((32*jt + 8*g) ^ swz)) = pk;
        }
        bf16x8 ch0 = *(const bf16x8*)(hrow + ((16*g) ^ swz));
        bf16x8 ch1 = *(const bf16x8*)(hrow + ((64 + 16*g) ^ swz));
        // stage 3 (0.125 pre-folded)
        f32x4 z3 = {0.f,0.f,0.f,0.f};
        f32x4 mx = __builtin_amdgcn_mfma_f32_16x16x32_bf16(w3f[0], ch0, z3, 0,0,0);
        mx = __builtin_amdgcn_mfma_f32_16x16x32_bf16(w3f[1], ch1, mx, 0,0,0);
        if (g < 2)
            *(f32x4*)(mixbuf + (16*nt + c)*12 + 4*g) = mx;
    }

    long e = base + l;
    const float* mr = mixbuf + l*12;
    float mm0=mr[0], mm1=mr[1], mm2=mr[2], mm3=mr[3];
    float mm4=mr[4], mm5=mr[5], mm6=mr[6], mm7=mr[7];
    int sn = snd_s[e];
    float se = su[sn];
    float ve[6];
    #pragma unroll
    for (int i=0;i<6;i++) ve[i] = vu[sn*6+i];
    float nh[3];
    #pragma unroll
    for (int i=0;i<3;i++) nh[i] = nhat[e*3+i];
    float vd0 = ve[0]*nh[0]+ve[1]*nh[1]+ve[2]*nh[2];
    float vd1 = ve[3]*nh[0]+ve[4]*nh[1]+ve[5]*nh[2];
    float* mp = msg + e*18;
    mp[0] = se *mm0;
    mp[1] = vd0*mm1;
    mp[2] = vd1*mm2;
    #pragma unroll
    for (int i=0;i<3;i++){
        mp[3 +i] = ve[i]*mm3;
        mp[6 +i] = ve[3+i]*mm4;
        mp[9 +i] = kC121*(vd0*nh[i]-ve[i]*(1.f/3.f))*mm5;
        mp[12+i] = kC121*(vd1*nh[i]-ve[3+i]*(1.f/3.f))*mm6;
        mp[15+i] = kSqrt3*se*nh[i]*mm7;
    }
}

// fused: CSR row-sum + node update + next-layer node_pre (or final out)
__global__ void agg_update(const float* __restrict__ msg, const int* __restrict__ rowptr,
                           const float* __restrict__ Wds, const float* __restrict__ Wdv,
                           float* __restrict__ s_sc, float* __restrict__ v_sc,
                           float* __restrict__ su, float* __restrict__ vu,
                           const float* __restrict__ Wss_n, const float* __restrict__ Wsv_n,
                           const float* __restrict__ Wus_n, const float* __restrict__ Wuv_n,
                           float* __restrict__ out, int is_last){
    int n = blockIdx.x*blockDim.x + threadIdx.x;
    if (n >= NN) return;
    float acc[18];
    #pragma unroll
    for (int c=0;c<18;c++) acc[c]=0.f;
    int b = rowptr[n], e2 = rowptr[n+1];
    for (int sIdx=b; sIdx<e2; ++sIdx){
        const float* mp = msg + (size_t)sIdx*18;
        #pragma unroll
        for (int c=0;c<18;c++) acc[c] += mp[c];
    }
    float st[3];
    #pragma unroll
    for (int i=0;i<3;i++)
        st[i] = (acc[0]*Wds[0*3+i]+acc[1]*Wds[1*3+i]+acc[2]*Wds[2*3+i])*kInvSqrt3 + s_sc[n*3+i];
    float vt[6];
    #pragma unroll
    for (int k=0;k<2;k++)
        #pragma unroll
        for (int c=0;c<3;c++){
            float a = 0.f;
            #pragma unroll
            for (int m=0;m<5;m++) a += acc[3+m*3+c]*Wdv[m*2+k];
            vt[k*3+c] = a*kInvSqrt5 + v_sc[n*6+k*3+c];
        }
    float snew = swishf(st[0]);
    float g1 = swishf(st[1]), g2 = swishf(st[2]);
    float nv[6];
    #pragma unroll
    for (int c=0;c<3;c++){ nv[c] = vt[c]*g1; nv[3+c] = vt[3+c]*g2; }
    if (is_last){
        #pragma unroll
        for (int c=0;c<3;c++) out[n*3+c] = nv[c];
    } else {
        #pragma unroll
        for (int i=0;i<3;i++) s_sc[n*3+i] = snew*Wss_n[i];
        #pragma unroll
        for (int k=0;k<2;k++)
            #pragma unroll
            for (int c=0;c<3;c++)
                v_sc[n*6+k*3+c] = (nv[c]*Wsv_n[0*2+k] + nv[3+c]*Wsv_n[1*2+k]) * kInvSqrt2;
        su[n] = snew * Wus_n[0];
        #pragma unroll
        for (int k=0;k<2;k++)
            #pragma unroll
            for (int c=0;c<3;c++)
                vu[n*6+k*3+c] = (nv[c]*Wuv_n[0*2+k] + nv[3+c]*Wuv_n[1*2+k]) * kInvSqrt2;
    }
}

// ---- fallback path (atomics + scalar MLP) ------------------------------
__global__ void node_init(const float* __restrict__ nf,
                          float* __restrict__ s, float* __restrict__ v){
    int n = blockIdx.x*blockDim.x + threadIdx.x;
    if (n >= NN) return;
    s[n] = nf[n*7];
    #pragma unroll
    for (int i=0;i<6;i++) v[n*6+i] = nf[n*7+1+i];
}

__global__ void node_pre(const float* __restrict__ s, const float* __restrict__ v,
                         const float* __restrict__ Wss, const float* __restrict__ Wsv,
                         const float* __restrict__ Wus, const float* __restrict__ Wuv,
                         float* __restrict__ s_sc, float* __restrict__ v_sc,
                         float* __restrict__ su, float* __restrict__ vu){
    int n = blockIdx.x*blockDim.x + threadIdx.x;
    if (n >= NN) return;
    float sv = s[n];
    float vv[6];
    #pragma unroll
    for (int i=0;i<6;i++) vv[i] = v[n*6+i];
    #pragma unroll
    for (int i=0;i<3;i++) s_sc[n*3+i] = sv*Wss[i];
    #pragma unroll
    for (int k=0;k<2;k++)
        #pragma unroll
        for (int c=0;c<3;c++)
            v_sc[n*6+k*3+c] = (vv[c]*Wsv[0*2+k] + vv[3+c]*Wsv[1*2+k]) * kInvSqrt2;
    su[n] = sv * Wus[0];
    #pragma unroll
    for (int k=0;k<2;k++)
        #pragma unroll
        for (int c=0;c<3;c++)
            vu[n*6+k*3+c] = (vv[c]*Wuv[0*2+k] + vv[3+c]*Wuv[1*2+k]) * kInvSqrt2;
}

__global__ void __launch_bounds__(256, 3) edge_msg_atomic(
    const int* __restrict__ snd, const int* __restrict__ rcv,
    const float* __restrict__ nhat, const float* __restrict__ radial,
    const float* __restrict__ su, const float* __restrict__ vu,
    const float* __restrict__ W1T, const float* __restrict__ W2,
    const float* __restrict__ W3,
    float* __restrict__ aggs, float* __restrict__ aggv){
    int e = blockIdx.x*blockDim.x + threadIdx.x;
    if (e >= NE) return;

    float r0 = radial[e*8+0], r1 = radial[e*8+1], r2 = radial[e*8+2], r3 = radial[e*8+3];
    float r4 = radial[e*8+4], r5 = radial[e*8+5], r6 = radial[e*8+6], r7 = radial[e*8+7];

    MLP_BODY

    int sn = snd[e], rn = rcv[e];
    float se = su[sn];
    float ve[6];
    #pragma unroll
    for (int i=0;i<6;i++) ve[i] = vu[sn*6+i];
    float nh[3];
    #pragma unroll
    for (int c=0;c<3;c++) nh[c] = nhat[e*3+c];
    float vd0 = ve[0]*nh[0]+ve[1]*nh[1]+ve[2]*nh[2];
    float vd1 = ve[3]*nh[0]+ve[4]*nh[1]+ve[5]*nh[2];

    atomicAdd(&aggs[rn*3+0], se *m0);
    atomicAdd(&aggs[rn*3+1], vd0*m1);
    atomicAdd(&aggs[rn*3+2], vd1*m2);
    #pragma unroll
    for (int c=0;c<3;c++){
        atomicAdd(&aggv[rn*15+0 +c], ve[c]*m3);
        atomicAdd(&aggv[rn*15+3 +c], ve[3+c]*m4);
        atomicAdd(&aggv[rn*15+6 +c], kC121*(vd0*nh[c]-ve[c]*(1.f/3.f))*m5);
        atomicAdd(&aggv[rn*15+9 +c], kC121*(vd1*nh[c]-ve[3+c]*(1.f/3.f))*m6);
        atomicAdd(&aggv[rn*15+12+c], kSqrt3*se*nh[c]*m7);
    }
}

__global__ void node_post_split(const float* __restrict__ aggs, const float* __restrict__ aggv,
                                const float* __restrict__ Wds, const float* __restrict__ Wdv,
                                const float* __restrict__ s_sc, const float* __restrict__ v_sc,
                                float* __restrict__ s, float* __restrict__ v,
                                float* __restrict__ out, int is_last){
    int n = blockIdx.x*blockDim.x + threadIdx.x;
    if (n >= NN) return;
    float as[3];
    #pragma unroll
    for (int j=0;j<3;j++) as[j] = aggs[n*3+j];
    float st[3];
    #pragma unroll
    for (int i=0;i<3;i++)
        st[i] = (as[0]*Wds[0*3+i]+as[1]*Wds[1*3+i]+as[2]*Wds[2*3+i])*kInvSqrt3 + s_sc[n*3+i];
    float vt[6];
    #pragma unroll
    for (int k=0;k<2;k++)
        #pragma unroll
        for (int c=0;c<3;c++){
            float acc = 0.f;
            #pragma unroll
            for (int m=0;m<5;m++) acc += aggv[n*15+m*3+c]*Wdv[m*2+k];
            vt[k*3+c] = acc*kInvSqrt5 + v_sc[n*6+k*3+c];
        }
    float snew = swishf(st[0]);
    float g1 = swishf(st[1]), g2 = swishf(st[2]);
    s[n] = snew;
    #pragma unroll
    for (int c=0;c<3;c++){
        float v0 = vt[c]*g1;
        float v1 = vt[3+c]*g2;
        v[n*6+c]   = v0;
        v[n*6+3+c] = v1;
        if (is_last) out[n*3+c] = v0;
    }
}

extern "C" void kernel_launch(void* const* d_in, const int* in_sizes, int n_in,
                              void* d_out, int out_size, void* d_ws, size_t ws_size,
                              hipStream_t stream){
    const float* pos = (const float*)d_in[0];
    const float* nf  = (const float*)d_in[1];
    const int*   snd = (const int*)d_in[2];
    const int*   rcv = (const int*)d_in[3];
    const float* Wss = (const float*)d_in[4];
    const float* Wsv = (const float*)d_in[5];
    const float* Wus = (const float*)d_in[6];
    const float* Wuv = (const float*)d_in[7];
    const float* W1  = (const float*)d_in[8];
    const float* W2  = (const float*)d_in[9];
    const float* W3  = (const float*)d_in[10];
    const float* Wds = (const float*)d_in[11];
    const float* Wdv = (const float*)d_in[12];
    float* out = (float*)d_out;

    dim3 blk(256);
    dim3 gE((NE+255)/256), gN((NN+255)/256);

    // sorted path: floats NE*21 + NN*16, ushorts NE*8 + 21504, ints NN*3+1+NE*2
    size_t need_sorted = ((size_t)NE*21 + (size_t)NN*16)*4
                       + ((size_t)NE*8 + 21504)*2
                       + ((size_t)NN*3 + 1 + (size_t)NE*2)*4 + 64;

    if (ws_size >= need_sorted){
        float* p = (float*)d_ws;
        float* nhat_s  = p; p += (size_t)NE*3;
        float* msg     = p; p += (size_t)NE*18;
        float* s_sc    = p; p += NN*3;
        float* v_sc    = p; p += NN*6;
        float* su      = p; p += NN;
        float* vu      = p; p += NN*6;
        unsigned short* wp = (unsigned short*)p;
        unsigned short* radial_bf = wp;    wp += (size_t)NE*8;
        unsigned short* W1F = wp;          wp += 3*4*64*8;
        unsigned short* W2F = wp;          wp += 3*2*4*64*8;
        unsigned short* W3F = wp;          wp += 3*2*64*8;
        int* ip = (int*)wp;
        int* cnt    = ip; ip += NN;
        int* rowptr = ip; ip += NN+1;
        int* wcur   = ip; ip += NN;
        int* slot   = ip; ip += NE;
        int* snd_s  = ip; ip += NE;

        build_frags<<<dim3(48), blk, 0, stream>>>(W1, W2, W3, W1F, W2F, W3F);
        hipMemsetAsync(cnt, 0, NN*sizeof(int), stream);
        hist_rcv<<<gE, blk, 0, stream>>>(rcv, cnt);
        exscan<<<dim3(1), dim3(1024), 0, stream>>>(cnt, rowptr, wcur);
        scatter_edges<<<gE, blk, 0, stream>>>(snd, rcv, wcur, slot, snd_s);
        edge_geom<<<gE, blk, 0, stream>>>(pos, snd, rcv, slot, nhat_s, nullptr, radial_bf);
        node_init_pre<<<gN, blk, 0, stream>>>(nf, Wss, Wsv, Wus, Wuv, s_sc, v_sc, su, vu);
        dim3 gW((NE/64 + 3)/4);
        for (int l=0;l<3;l++){
            edge_msg_mfma<<<gW, blk, 0, stream>>>(
                snd_s, nhat_s, radial_bf, su, vu,
                W1F + l*2048, W2F + l*4096, W3F + l*1024, msg);
            int nl = (l<2) ? l+1 : 0;   // weights unused when is_last
            agg_update<<<gN, blk, 0, stream>>>(
                msg, rowptr, Wds+l*9, Wdv+l*10,
                s_sc, v_sc, su, vu,
                Wss+nl*3, Wsv+nl*4, Wus+nl, Wuv+nl*4,
                out, (l==2)?1:0);
        }
    } else {
        float* p = (float*)d_ws;
        float* nhat   = p; p += (size_t)NE*3;
        float* radial = p; p += (size_t)NE*8;
        float* s      = p; p += NN;
        float* v      = p; p += NN*6;
        float* s_sc   = p; p += NN*3;
        float* v_sc   = p; p += NN*6;
        float* su     = p; p += NN;
        float* vu     = p; p += NN*6;
        float* aggs   = p; p += NN*3;
        float* aggv   = p; p += NN*15;
        float* W1T    = p; p += 1536;

        transpose_w1<<<dim3((1536+255)/256), blk, 0, stream>>>(W1, W1T);
        edge_geom<<<gE, blk, 0, stream>>>(pos, snd, rcv, nullptr, nhat, radial, nullptr);
        node_init<<<gN, blk, 0, stream>>>(nf, s, v);
        for (int l=0;l<3;l++){
            node_pre<<<gN, blk, 0, stream>>>(
                s, v, Wss+l*3, Wsv+l*4, Wus+l, Wuv+l*4, s_sc, v_sc, su, vu);
            hipMemsetAsync(aggs, 0, NN*3*sizeof(float), stream);
            hipMemsetAsync(aggv, 0, NN*15*sizeof(float), stream);
            edge_msg_atomic<<<gE, blk, 0, stream>>>(
                snd, rcv, nhat, radial, su, vu,
                W1T+l*512, W2+l*4096, W3+l*512, aggs, aggv);
            node_post_split<<<gN, blk, 0, stream>>>(
                aggs, aggv, Wds+l*9, Wdv+l*10, s_sc, v_sc, s, v, out, (l==2)?1:0);
        }
    }
}

// Round 14
// 385.791 us; speedup vs baseline: 2.7431x; 1.2430x over previous
//
#include <hip/hip_runtime.h>
#include <hip/hip_bf16.h>
#include <math.h>

#define NN 50000
#define NE 1000000

typedef __attribute__((ext_vector_type(8))) short bf16x8;
typedef __attribute__((ext_vector_type(4))) float f32x4;

constexpr float kC121    = 2.1213203435596424f;
constexpr float kSqrt3   = 1.7320508075688772f;
constexpr float kInvSqrt2= 0.7071067811865475f;
constexpr float kInvSqrt8= 0.35355339059327373f;
constexpr float kInvSqrt3= 0.5773502691896258f;
constexpr float kInvSqrt5= 0.4472135954999579f;
constexpr float kSqrt2   = 1.4142135623730951f;
constexpr float kPi      = 3.14159265358979323846f;

__device__ __forceinline__ float swishf(float x){
    return x * __builtin_amdgcn_rcpf(1.0f + __expf(-x));
}
__device__ __forceinline__ unsigned short f2bf(float f){
    unsigned int u = __float_as_uint(f);
    u += 0x7fffu + ((u>>16)&1u);
    return (unsigned short)(u>>16);
}
__device__ __forceinline__ unsigned int pk2(float a, float b){
    union { __hip_bfloat162 h; unsigned int u; } cv;
    cv.h = __float22bfloat162_rn(make_float2(a,b));
    return cv.u;
}

// one 32B record per edge in RECEIVER-SORTED order: single scatter stream
struct __align__(16) EdgeRec {
    uint4 rad;              // 8 bf16 radial
    float nx, ny, nz;       // nhat f32
    int   sn;               // sender
};

// ---- scalar-MLP macros (fallback path only) ----------------------------
#define REP64A(M) M(0) M(1) M(2) M(3) M(4) M(5) M(6) M(7) M(8) M(9) \
 M(10) M(11) M(12) M(13) M(14) M(15) M(16) M(17) M(18) M(19) \
 M(20) M(21) M(22) M(23) M(24) M(25) M(26) M(27) M(28) M(29) \
 M(30) M(31) M(32) M(33) M(34) M(35) M(36) M(37) M(38) M(39) \
 M(40) M(41) M(42) M(43) M(44) M(45) M(46) M(47) M(48) M(49) \
 M(50) M(51) M(52) M(53) M(54) M(55) M(56) M(57) M(58) M(59) \
 M(60) M(61) M(62) M(63)
#define REP64B(M) M(0) M(1) M(2) M(3) M(4) M(5) M(6) M(7) M(8) M(9) \
 M(10) M(11) M(12) M(13) M(14) M(15) M(16) M(17) M(18) M(19) \
 M(20) M(21) M(22) M(23) M(24) M(25) M(26) M(27) M(28) M(29) \
 M(30) M(31) M(32) M(33) M(34) M(35) M(36) M(37) M(38) M(39) \
 M(40) M(41) M(42) M(43) M(44) M(45) M(46) M(47) M(48) M(49) \
 M(50) M(51) M(52) M(53) M(54) M(55) M(56) M(57) M(58) M(59) \
 M(60) M(61) M(62) M(63)
#define STAGE1(J) float h_##J; { const float* w = W1T + (J)*8; \
    float a = fmaf(r0,w[0],fmaf(r1,w[1],fmaf(r2,w[2],fmaf(r3,w[3], \
              fmaf(r4,w[4],fmaf(r5,w[5],fmaf(r6,w[6],r7*w[7]))))))); \
    h_##J = swishf(a*kInvSqrt8); }
#define DECLACC(J) float acc_##J = 0.f;
#define UPD(J) acc_##J = fmaf(hk, w2r[J], acc_##J);
#define KSTEP(K) { float hk = h_##K; const float* w2r = W2 + (K)*64; REP64B(UPD) }
#define S3(J) { float a = swishf(acc_##J*0.125f); const float* w3 = W3 + (J)*8; \
    m0=fmaf(a,w3[0],m0); m1=fmaf(a,w3[1],m1); m2=fmaf(a,w3[2],m2); m3=fmaf(a,w3[3],m3); \
    m4=fmaf(a,w3[4],m4); m5=fmaf(a,w3[5],m5); m6=fmaf(a,w3[6],m6); m7=fmaf(a,w3[7],m7); }
#define MLP_BODY \
    float m0=0.f,m1=0.f,m2=0.f,m3=0.f,m4=0.f,m5=0.f,m6=0.f,m7=0.f; \
    { REP64A(STAGE1) REP64A(DECLACC) REP64A(KSTEP) REP64A(S3) } \
    m0*=0.125f; m1*=0.125f; m2*=0.125f; m3*=0.125f; \
    m4*=0.125f; m5*=0.125f; m6*=0.125f; m7*=0.125f;

// ------------------------------------------------------------------------

__global__ void transpose_w1(const float* __restrict__ W1, float* __restrict__ W1T){
    int i = blockIdx.x*blockDim.x + threadIdx.x;
    if (i < 3*8*64){
        int l = i/512, r = i%512; int k = r/64, j = r%64;
        W1T[l*512 + j*8 + k] = W1[i];
    }
}

// Pack W1/W2/W3 into per-lane MFMA A-fragments (bf16), assumed k-map k=8g+i.
// Stage scales folded: W1*=1/sqrt8, W2*=0.125, W3*=0.125.
__global__ void build_frags(const float* __restrict__ W1, const float* __restrict__ W2,
                            const float* __restrict__ W3,
                            unsigned short* __restrict__ W1F,
                            unsigned short* __restrict__ W2F,
                            unsigned short* __restrict__ W3F){
    int t = blockIdx.x*blockDim.x + threadIdx.x;
    if (t < 3*4*64*8){
        int i=t&7, lane=(t>>3)&63, jt=(t>>9)&3, l=t>>11;
        int g=lane>>4, c=lane&15;
        int k=8*g+i, j=16*jt+c;
        float v = (k<8) ? W1[l*512 + k*64 + j]*kInvSqrt8 : 0.f;
        W1F[t] = f2bf(v);
    }
    if (t < 3*2*4*64*8){
        int i=t&7, lane=(t>>3)&63, jt=(t>>9)&3, kt=(t>>11)&1, l=t>>12;
        int g=lane>>4, c=lane&15;
        int k=32*kt+8*g+i, j=16*jt+c;
        W2F[t] = f2bf(W2[l*4096 + k*64 + j]*0.125f);
    }
    if (t < 3*2*64*8){
        int i=t&7, lane=(t>>3)&63, kt=(t>>9)&1, l=t>>10;
        int g=lane>>4, c=lane&15;
        int k=32*kt+8*g+i;
        float v = (c<8) ? W3[l*512 + k*8 + c]*0.125f : 0.f;
        W3F[t] = f2bf(v);
    }
}

// ---- CSR build: ONE atomic pass (rank folded into histogram) -----------
__global__ void hist_rank(const int* __restrict__ rcv, int* __restrict__ cnt,
                          int* __restrict__ lrank){
    int e = blockIdx.x*blockDim.x + threadIdx.x;
    if (e < NE) lrank[e] = atomicAdd(&cnt[rcv[e]], 1);
}

__global__ void exscan(const int* __restrict__ cnt, int* __restrict__ rowptr){
    __shared__ int wsum[16];
    __shared__ int carry_s;
    int tid = threadIdx.x;
    int lane = tid & 63, wv = tid >> 6;
    if (tid==0) carry_s = 0;
    __syncthreads();
    for (int base=0; base<NN; base+=4096){
        int i0 = base + tid*4;
        int v0 = (i0+0<NN)?cnt[i0+0]:0;
        int v1 = (i0+1<NN)?cnt[i0+1]:0;
        int v2 = (i0+2<NN)?cnt[i0+2]:0;
        int v3 = (i0+3<NN)?cnt[i0+3]:0;
        int t = v0+v1+v2+v3;
        int sc = t;
        #pragma unroll
        for (int off=1; off<64; off<<=1){
            int u = __shfl_up(sc, off, 64);
            if (lane >= off) sc += u;
        }
        if (lane==63) wsum[wv] = sc;
        __syncthreads();
        if (wv==0 && lane<16){
            int ws = wsum[lane];
            #pragma unroll
            for (int off=1; off<16; off<<=1){
                int u = __shfl_up(ws, off, 64);
                if (lane>=off) ws += u;
            }
            wsum[lane] = ws;
        }
        __syncthreads();
        int carry = carry_s;
        int wbase = (wv==0)?0:wsum[wv-1];
        int ex = carry + wbase + (sc - t);
        if (i0+0<NN) rowptr[i0+0]=ex; ex += v0;
        if (i0+1<NN) rowptr[i0+1]=ex; ex += v1;
        if (i0+2<NN) rowptr[i0+2]=ex; ex += v2;
        if (i0+3<NN) rowptr[i0+3]=ex;
        __syncthreads();
        if (tid==0) carry_s = carry + wsum[15];
        __syncthreads();
    }
    if (threadIdx.x==0) rowptr[NN] = carry_s;
}

// geometry -> single 32B scattered record at sorted slot rowptr[r]+lrank[e]
__global__ void edge_geom_rec(const float* __restrict__ pos,
                              const int* __restrict__ snd,
                              const int* __restrict__ rcv,
                              const int* __restrict__ rowptr,
                              const int* __restrict__ lrank,
                              EdgeRec* __restrict__ rec){
    int e = blockIdx.x*blockDim.x + threadIdx.x;
    if (e >= NE) return;
    int s = snd[e], r = rcv[e];
    float vx = pos[r*3+0]-pos[s*3+0];
    float vy = pos[r*3+1]-pos[s*3+1];
    float vz = pos[r*3+2]-pos[s*3+2];
    float len = sqrtf(vx*vx+vy*vy+vz*vz);
    float safe = (len==0.f)?1.f:len;
    float inv = 1.f/safe;
    float x = len;
    float x3=x*x*x, x6=x3*x3, x7=x6*x, x8=x7*x;
    float poly = 1.f - 28.f*x6 + 48.f*x7 - 21.f*x8;
    float env = (x<1.f)?poly:0.f;
    float c = kSqrt2*env*inv;
    float s1, c1;
    __sincosf(kPi*len, &s1, &c1);
    float tc = 2.f*c1;
    float sk_m1 = 0.f, sk = s1;
    float zero = (len==0.f)?0.f:1.f;
    float rv[8];
    #pragma unroll
    for (int k=1;k<=8;k++){
        rv[k-1] = sk*c*zero;
        float nxt = tc*sk - sk_m1;
        sk_m1 = sk; sk = nxt;
    }
    EdgeRec rc;
    rc.rad.x = pk2(rv[0],rv[1]); rc.rad.y = pk2(rv[2],rv[3]);
    rc.rad.z = pk2(rv[4],rv[5]); rc.rad.w = pk2(rv[6],rv[7]);
    rc.nx = vx*inv; rc.ny = vy*inv; rc.nz = vz*inv;
    rc.sn = s;
    int p = rowptr[r] + lrank[e];
    rec[p] = rc;
}

// prologue: node_init + node_pre(l=0) fused
__global__ void node_init_pre(const float* __restrict__ nf,
                              const float* __restrict__ Wss, const float* __restrict__ Wsv,
                              const float* __restrict__ Wus, const float* __restrict__ Wuv,
                              float* __restrict__ s_sc, float* __restrict__ v_sc,
                              float* __restrict__ su, float* __restrict__ vu){
    int n = blockIdx.x*blockDim.x + threadIdx.x;
    if (n >= NN) return;
    float sv = nf[n*7];
    float vv[6];
    #pragma unroll
    for (int i=0;i<6;i++) vv[i] = nf[n*7+1+i];
    #pragma unroll
    for (int i=0;i<3;i++) s_sc[n*3+i] = sv*Wss[i];
    #pragma unroll
    for (int k=0;k<2;k++)
        #pragma unroll
        for (int c=0;c<3;c++)
            v_sc[n*6+k*3+c] = (vv[c]*Wsv[0*2+k] + vv[3+c]*Wsv[1*2+k]) * kInvSqrt2;
    su[n] = sv * Wus[0];
    #pragma unroll
    for (int k=0;k<2;k++)
        #pragma unroll
        for (int c=0;c<3;c++)
            vu[n*6+k*3+c] = (vv[c]*Wuv[0*2+k] + vv[3+c]*Wuv[1*2+k]) * kInvSqrt2;
}

// ---- MFMA edge kernel: all per-edge inputs from one 32B record ---------
__global__ void __launch_bounds__(256) edge_msg_mfma(
    const EdgeRec* __restrict__ rec,
    const float* __restrict__ su, const float* __restrict__ vu,
    const unsigned short* __restrict__ W1F, const unsigned short* __restrict__ W2F,
    const unsigned short* __restrict__ W3F,
    float* __restrict__ msg){
    __shared__ unsigned short hbuf_s[4][16*72];
    __shared__ float mixbuf_s[4][64*12];
    int tid = threadIdx.x;
    int w = tid>>6, l = tid&63;
    int g = l>>4, c = l&15;
    long base = ((long)blockIdx.x*4 + w)*64;
    if (base >= NE) return;
    char* hrow = (char*)hbuf_s[w] + c*144;
    float* mixbuf = mixbuf_s[w];
    int swz = (c&7)<<4;

    bf16x8 w1f[4], w2f[2][4], w3f[2];
    #pragma unroll
    for (int jt=0;jt<4;jt++)
        w1f[jt] = *(const bf16x8*)(W1F + (jt*64 + l)*8);
    #pragma unroll
    for (int kt=0;kt<2;kt++)
        #pragma unroll
        for (int jt=0;jt<4;jt++)
            w2f[kt][jt] = *(const bf16x8*)(W2F + ((kt*4+jt)*64 + l)*8);
    #pragma unroll
    for (int kt=0;kt<2;kt++)
        w3f[kt] = *(const bf16x8*)(W3F + (kt*64 + l)*8);

    #pragma unroll 1
    for (int nt=0; nt<4; ++nt){
        bf16x8 brad = {0,0,0,0,0,0,0,0};
        if (g==0)
            brad = *(const bf16x8*)&rec[base + 16*nt + c].rad;
        #pragma unroll
        for (int jt=0;jt<4;jt++){
            f32x4 z = {0.f,0.f,0.f,0.f};
            f32x4 d1 = __builtin_amdgcn_mfma_f32_16x16x32_bf16(w1f[jt], brad, z, 0,0,0);
            uint2 pk;
            pk.x = pk2(swishf(d1[0]), swishf(d1[1]));
            pk.y = pk2(swishf(d1[2]), swishf(d1[3]));
            *(uint2*)(hrow + ((32*jt + 8*g) ^ swz)) = pk;
        }
        bf16x8 bh0 = *(const bf16x8*)(hrow + ((16*g) ^ swz));
        bf16x8 bh1 = *(const bf16x8*)(hrow + ((64 + 16*g) ^ swz));
        #pragma unroll
        for (int jt=0;jt<4;jt++){
            f32x4 z = {0.f,0.f,0.f,0.f};
            f32x4 d2 = __builtin_amdgcn_mfma_f32_16x16x32_bf16(w2f[0][jt], bh0, z, 0,0,0);
            d2 = __builtin_amdgcn_mfma_f32_16x16x32_bf16(w2f[1][jt], bh1, d2, 0,0,0);
            uint2 pk;
            pk.x = pk2(swishf(d2[0]), swishf(d2[1]));
            pk.y = pk2(swishf(d2[2]), swishf(d2[3]));
            *(uint2*)(hrow + ((32*jt + 8*g) ^ swz)) = pk;
        }
        bf16x8 ch0 = *(const bf16x8*)(hrow + ((16*g) ^ swz));
        bf16x8 ch1 = *(const bf16x8*)(hrow + ((64 + 16*g) ^ swz));
        f32x4 z3 = {0.f,0.f,0.f,0.f};
        f32x4 mx = __builtin_amdgcn_mfma_f32_16x16x32_bf16(w3f[0], ch0, z3, 0,0,0);
        mx = __builtin_amdgcn_mfma_f32_16x16x32_bf16(w3f[1], ch1, mx, 0,0,0);
        if (g < 2)
            *(f32x4*)(mixbuf + (16*nt + c)*12 + 4*g) = mx;
    }

    long e = base + l;
    EdgeRec r = rec[e];
    const float* mr = mixbuf + l*12;
    float mm0=mr[0], mm1=mr[1], mm2=mr[2], mm3=mr[3];
    float mm4=mr[4], mm5=mr[5], mm6=mr[6], mm7=mr[7];
    float se = su[r.sn];
    float ve[6];
    #pragma unroll
    for (int i=0;i<6;i++) ve[i] = vu[r.sn*6+i];
    float nh[3] = { r.nx, r.ny, r.nz };
    float vd0 = ve[0]*nh[0]+ve[1]*nh[1]+ve[2]*nh[2];
    float vd1 = ve[3]*nh[0]+ve[4]*nh[1]+ve[5]*nh[2];
    float* mp = msg + e*18;
    mp[0] = se *mm0;
    mp[1] = vd0*mm1;
    mp[2] = vd1*mm2;
    #pragma unroll
    for (int i=0;i<3;i++){
        mp[3 +i] = ve[i]*mm3;
        mp[6 +i] = ve[3+i]*mm4;
        mp[9 +i] = kC121*(vd0*nh[i]-ve[i]*(1.f/3.f))*mm5;
        mp[12+i] = kC121*(vd1*nh[i]-ve[3+i]*(1.f/3.f))*mm6;
        mp[15+i] = kSqrt3*se*nh[i]*mm7;
    }
}

// fused: CSR row-sum + node update + next-layer node_pre (or final out)
__global__ void agg_update(const float* __restrict__ msg, const int* __restrict__ rowptr,
                           const float* __restrict__ Wds, const float* __restrict__ Wdv,
                           float* __restrict__ s_sc, float* __restrict__ v_sc,
                           float* __restrict__ su, float* __restrict__ vu,
                           const float* __restrict__ Wss_n, const float* __restrict__ Wsv_n,
                           const float* __restrict__ Wus_n, const float* __restrict__ Wuv_n,
                           float* __restrict__ out, int is_last){
    int n = blockIdx.x*blockDim.x + threadIdx.x;
    if (n >= NN) return;
    float acc[18];
    #pragma unroll
    for (int c=0;c<18;c++) acc[c]=0.f;
    int b = rowptr[n], e2 = rowptr[n+1];
    for (int sIdx=b; sIdx<e2; ++sIdx){
        const float* mp = msg + (size_t)sIdx*18;
        #pragma unroll
        for (int c=0;c<18;c++) acc[c] += mp[c];
    }
    float st[3];
    #pragma unroll
    for (int i=0;i<3;i++)
        st[i] = (acc[0]*Wds[0*3+i]+acc[1]*Wds[1*3+i]+acc[2]*Wds[2*3+i])*kInvSqrt3 + s_sc[n*3+i];
    float vt[6];
    #pragma unroll
    for (int k=0;k<2;k++)
        #pragma unroll
        for (int c=0;c<3;c++){
            float a = 0.f;
            #pragma unroll
            for (int m=0;m<5;m++) a += acc[3+m*3+c]*Wdv[m*2+k];
            vt[k*3+c] = a*kInvSqrt5 + v_sc[n*6+k*3+c];
        }
    float snew = swishf(st[0]);
    float g1 = swishf(st[1]), g2 = swishf(st[2]);
    float nv[6];
    #pragma unroll
    for (int c=0;c<3;c++){ nv[c] = vt[c]*g1; nv[3+c] = vt[3+c]*g2; }
    if (is_last){
        #pragma unroll
        for (int c=0;c<3;c++) out[n*3+c] = nv[c];
    } else {
        #pragma unroll
        for (int i=0;i<3;i++) s_sc[n*3+i] = snew*Wss_n[i];
        #pragma unroll
        for (int k=0;k<2;k++)
            #pragma unroll
            for (int c=0;c<3;c++)
                v_sc[n*6+k*3+c] = (nv[c]*Wsv_n[0*2+k] + nv[3+c]*Wsv_n[1*2+k]) * kInvSqrt2;
        su[n] = snew * Wus_n[0];
        #pragma unroll
        for (int k=0;k<2;k++)
            #pragma unroll
            for (int c=0;c<3;c++)
                vu[n*6+k*3+c] = (nv[c]*Wuv_n[0*2+k] + nv[3+c]*Wuv_n[1*2+k]) * kInvSqrt2;
    }
}

// ---- fallback path (atomics + scalar MLP) ------------------------------
__global__ void edge_geom_flat(const float* __restrict__ pos,
                               const int* __restrict__ snd,
                               const int* __restrict__ rcv,
                               float* __restrict__ nhat,
                               float* __restrict__ radial){
    int e = blockIdx.x*blockDim.x + threadIdx.x;
    if (e >= NE) return;
    int s = snd[e], r = rcv[e];
    float vx = pos[r*3+0]-pos[s*3+0];
    float vy = pos[r*3+1]-pos[s*3+1];
    float vz = pos[r*3+2]-pos[s*3+2];
    float len = sqrtf(vx*vx+vy*vy+vz*vz);
    float safe = (len==0.f)?1.f:len;
    float inv = 1.f/safe;
    nhat[e*3+0]=vx*inv; nhat[e*3+1]=vy*inv; nhat[e*3+2]=vz*inv;
    float x = len;
    float x3=x*x*x, x6=x3*x3, x7=x6*x, x8=x7*x;
    float poly = 1.f - 28.f*x6 + 48.f*x7 - 21.f*x8;
    float env = (x<1.f)?poly:0.f;
    float c = kSqrt2*env*inv;
    float s1, c1;
    __sincosf(kPi*len, &s1, &c1);
    float tc = 2.f*c1;
    float sk_m1 = 0.f, sk = s1;
    float zero = (len==0.f)?0.f:1.f;
    #pragma unroll
    for (int k=1;k<=8;k++){
        radial[e*8+k-1] = sk*c*zero;
        float nxt = tc*sk - sk_m1;
        sk_m1 = sk; sk = nxt;
    }
}

__global__ void node_init(const float* __restrict__ nf,
                          float* __restrict__ s, float* __restrict__ v){
    int n = blockIdx.x*blockDim.x + threadIdx.x;
    if (n >= NN) return;
    s[n] = nf[n*7];
    #pragma unroll
    for (int i=0;i<6;i++) v[n*6+i] = nf[n*7+1+i];
}

__global__ void node_pre(const float* __restrict__ s, const float* __restrict__ v,
                         const float* __restrict__ Wss, const float* __restrict__ Wsv,
                         const float* __restrict__ Wus, const float* __restrict__ Wuv,
                         float* __restrict__ s_sc, float* __restrict__ v_sc,
                         float* __restrict__ su, float* __restrict__ vu){
    int n = blockIdx.x*blockDim.x + threadIdx.x;
    if (n >= NN) return;
    float sv = s[n];
    float vv[6];
    #pragma unroll
    for (int i=0;i<6;i++) vv[i] = v[n*6+i];
    #pragma unroll
    for (int i=0;i<3;i++) s_sc[n*3+i] = sv*Wss[i];
    #pragma unroll
    for (int k=0;k<2;k++)
        #pragma unroll
        for (int c=0;c<3;c++)
            v_sc[n*6+k*3+c] = (vv[c]*Wsv[0*2+k] + vv[3+c]*Wsv[1*2+k]) * kInvSqrt2;
    su[n] = sv * Wus[0];
    #pragma unroll
    for (int k=0;k<2;k++)
        #pragma unroll
        for (int c=0;c<3;c++)
            vu[n*6+k*3+c] = (vv[c]*Wuv[0*2+k] + vv[3+c]*Wuv[1*2+k]) * kInvSqrt2;
}

__global__ void __launch_bounds__(256, 3) edge_msg_atomic(
    const int* __restrict__ snd, const int* __restrict__ rcv,
    const float* __restrict__ nhat, const float* __restrict__ radial,
    const float* __restrict__ su, const float* __restrict__ vu,
    const float* __restrict__ W1T, const float* __restrict__ W2,
    const float* __restrict__ W3,
    float* __restrict__ aggs, float* __restrict__ aggv){
    int e = blockIdx.x*blockDim.x + threadIdx.x;
    if (e >= NE) return;

    float r0 = radial[e*8+0], r1 = radial[e*8+1], r2 = radial[e*8+2], r3 = radial[e*8+3];
    float r4 = radial[e*8+4], r5 = radial[e*8+5], r6 = radial[e*8+6], r7 = radial[e*8+7];

    MLP_BODY

    int sn = snd[e], rn = rcv[e];
    float se = su[sn];
    float ve[6];
    #pragma unroll
    for (int i=0;i<6;i++) ve[i] = vu[sn*6+i];
    float nh[3];
    #pragma unroll
    for (int c=0;c<3;c++) nh[c] = nhat[e*3+c];
    float vd0 = ve[0]*nh[0]+ve[1]*nh[1]+ve[2]*nh[2];
    float vd1 = ve[3]*nh[0]+ve[4]*nh[1]+ve[5]*nh[2];

    atomicAdd(&aggs[rn*3+0], se *m0);
    atomicAdd(&aggs[rn*3+1], vd0*m1);
    atomicAdd(&aggs[rn*3+2], vd1*m2);
    #pragma unroll
    for (int c=0;c<3;c++){
        atomicAdd(&aggv[rn*15+0 +c], ve[c]*m3);
        atomicAdd(&aggv[rn*15+3 +c], ve[3+c]*m4);
        atomicAdd(&aggv[rn*15+6 +c], kC121*(vd0*nh[c]-ve[c]*(1.f/3.f))*m5);
        atomicAdd(&aggv[rn*15+9 +c], kC121*(vd1*nh[c]-ve[3+c]*(1.f/3.f))*m6);
        atomicAdd(&aggv[rn*15+12+c], kSqrt3*se*nh[c]*m7);
    }
}

__global__ void node_post_split(const float* __restrict__ aggs, const float* __restrict__ aggv,
                                const float* __restrict__ Wds, const float* __restrict__ Wdv,
                                const float* __restrict__ s_sc, const float* __restrict__ v_sc,
                                float* __restrict__ s, float* __restrict__ v,
                                float* __restrict__ out, int is_last){
    int n = blockIdx.x*blockDim.x + threadIdx.x;
    if (n >= NN) return;
    float as[3];
    #pragma unroll
    for (int j=0;j<3;j++) as[j] = aggs[n*3+j];
    float st[3];
    #pragma unroll
    for (int i=0;i<3;i++)
        st[i] = (as[0]*Wds[0*3+i]+as[1]*Wds[1*3+i]+as[2]*Wds[2*3+i])*kInvSqrt3 + s_sc[n*3+i];
    float vt[6];
    #pragma unroll
    for (int k=0;k<2;k++)
        #pragma unroll
        for (int c=0;c<3;c++){
            float acc = 0.f;
            #pragma unroll
            for (int m=0;m<5;m++) acc += aggv[n*15+m*3+c]*Wdv[m*2+k];
            vt[k*3+c] = acc*kInvSqrt5 + v_sc[n*6+k*3+c];
        }
    float snew = swishf(st[0]);
    float g1 = swishf(st[1]), g2 = swishf(st[2]);
    s[n] = snew;
    #pragma unroll
    for (int c=0;c<3;c++){
        float v0 = vt[c]*g1;
        float v1 = vt[3+c]*g2;
        v[n*6+c]   = v0;
        v[n*6+3+c] = v1;
        if (is_last) out[n*3+c] = v0;
    }
}

extern "C" void kernel_launch(void* const* d_in, const int* in_sizes, int n_in,
                              void* d_out, int out_size, void* d_ws, size_t ws_size,
                              hipStream_t stream){
    const float* pos = (const float*)d_in[0];
    const float* nf  = (const float*)d_in[1];
    const int*   snd = (const int*)d_in[2];
    const int*   rcv = (const int*)d_in[3];
    const float* Wss = (const float*)d_in[4];
    const float* Wsv = (const float*)d_in[5];
    const float* Wus = (const float*)d_in[6];
    const float* Wuv = (const float*)d_in[7];
    const float* W1  = (const float*)d_in[8];
    const float* W2  = (const float*)d_in[9];
    const float* W3  = (const float*)d_in[10];
    const float* Wds = (const float*)d_in[11];
    const float* Wdv = (const float*)d_in[12];
    float* out = (float*)d_out;

    dim3 blk(256);
    dim3 gE((NE+255)/256), gN((NN+255)/256);

    // sorted path: floats (NE*18 + NN*16), rec NE*32B, frags, ints
    size_t need_sorted = ((size_t)NE*18 + (size_t)NN*16)*4
                       + (size_t)NE*32
                       + 21504*2
                       + ((size_t)NN*2 + 1 + (size_t)NE)*4 + 64;

    if (ws_size >= need_sorted){
        float* p = (float*)d_ws;
        float* msg     = p; p += (size_t)NE*18;
        float* s_sc    = p; p += NN*3;
        float* v_sc    = p; p += NN*6;
        float* su      = p; p += NN;
        float* vu      = p; p += NN*6;
        EdgeRec* rec   = (EdgeRec*)p;
        unsigned short* wp = (unsigned short*)(rec + NE);
        unsigned short* W1F = wp;          wp += 3*4*64*8;
        unsigned short* W2F = wp;          wp += 3*2*4*64*8;
        unsigned short* W3F = wp;          wp += 3*2*64*8;
        int* ip = (int*)wp;
        int* cnt    = ip; ip += NN;
        int* rowptr = ip; ip += NN+1;
        int* lrank  = ip; ip += NE;

        build_frags<<<dim3(48), blk, 0, stream>>>(W1, W2, W3, W1F, W2F, W3F);
        hipMemsetAsync(cnt, 0, NN*sizeof(int), stream);
        hist_rank<<<gE, blk, 0, stream>>>(rcv, cnt, lrank);
        exscan<<<dim3(1), dim3(1024), 0, stream>>>(cnt, rowptr);
        edge_geom_rec<<<gE, blk, 0, stream>>>(pos, snd, rcv, rowptr, lrank, rec);
        node_init_pre<<<gN, blk, 0, stream>>>(nf, Wss, Wsv, Wus, Wuv, s_sc, v_sc, su, vu);
        dim3 gW((NE/64 + 3)/4);
        for (int l=0;l<3;l++){
            edge_msg_mfma<<<gW, blk, 0, stream>>>(
                rec, su, vu,
                W1F + l*2048, W2F + l*4096, W3F + l*1024, msg);
            int nl = (l<2) ? l+1 : 0;
            agg_update<<<gN, blk, 0, stream>>>(
                msg, rowptr, Wds+l*9, Wdv+l*10,
                s_sc, v_sc, su, vu,
                Wss+nl*3, Wsv+nl*4, Wus+nl, Wuv+nl*4,
                out, (l==2)?1:0);
        }
    } else {
        float* p = (float*)d_ws;
        float* nhat   = p; p += (size_t)NE*3;
        float* radial = p; p += (size_t)NE*8;
        float* s      = p; p += NN;
        float* v      = p; p += NN*6;
        float* s_sc   = p; p += NN*3;
        float* v_sc   = p; p += NN*6;
        float* su     = p; p += NN;
        float* vu     = p; p += NN*6;
        float* aggs   = p; p += NN*3;
        float* aggv   = p; p += NN*15;
        float* W1T    = p; p += 1536;

        transpose_w1<<<dim3((1536+255)/256), blk, 0, stream>>>(W1, W1T);
        edge_geom_flat<<<gE, blk, 0, stream>>>(pos, snd, rcv, nhat, radial);
        node_init<<<gN, blk, 0, stream>>>(nf, s, v);
        for (int l=0;l<3;l++){
            node_pre<<<gN, blk, 0, stream>>>(
                s, v, Wss+l*3, Wsv+l*4, Wus+l, Wuv+l*4, s_sc, v_sc, su, vu);
            hipMemsetAsync(aggs, 0, NN*3*sizeof(float), stream);
            hipMemsetAsync(aggv, 0, NN*15*sizeof(float), stream);
            edge_msg_atomic<<<gE, blk, 0, stream>>>(
                snd, rcv, nhat, radial, su, vu,
                W1T+l*512, W2+l*4096, W3+l*512, aggs, aggv);
            node_post_split<<<gN, blk, 0, stream>>>(
                aggs, aggv, Wds+l*9, Wdv+l*10, s_sc, v_sc, s, v, out, (l==2)?1:0);
        }
    }
}